// Round 12
// baseline (1998.425 us; speedup 1.0000x reference)
//
#include <hip/hip_runtime.h>
#include <hip/hip_bf16.h>
#include <math.h>

// GRUModel: B=64,S=288,Fc=16,Fo=32,D=256,QKV=64,HEADS=4,hd=16
// Round 12: revert R11 (4-wave scan regressed: 1 wave/SIMD has nothing to
// overlap dep chains with). New scan: 2 batches per block (16 waves, 2 groups
// of 8; inner wave shape identical to R10/R7-proven). Amortizes the ~780cyc
// per-step serial tail over 2 batch-steps; MFMA pipe time doubles per block
// but tails overlap across groups. grid 64 -> 32 blocks.
// Tail identical to R10 (weight-prep bf16 [N,K], fused gemms, bf16 attn path).
// ws layout (floats): X[NX] | Yb[NX] | G f32[NG] | C bf16[NX/2] | Wt[229K]

#define EPS 1e-5f
constexpr int B_ = 64, S_ = 288, FC = 16, FO = 32, D_ = 256, QKVN = 64, HD = 16;
constexpr int TOK = B_ * S_;            // 18432
constexpr int NX = TOK * D_;            // 4718592
constexpr int NG = TOK * 512;           // 9437184

typedef short bf16x8 __attribute__((ext_vector_type(8)));
typedef float f32x4 __attribute__((ext_vector_type(4)));

__device__ __forceinline__ short f2bf(float f) {
  __hip_bfloat16 h = __float2bfloat16(f);
  return __builtin_bit_cast(short, h);
}
__device__ __forceinline__ float b2f(__hip_bfloat16 h) {
  return __bfloat162float(h);
}

// block-wide sum; blockDim multiple of 64, <=512. sc: >= blockDim/64 floats.
__device__ __forceinline__ float blk_sum(float v, float* sc) {
  #pragma unroll
  for (int o = 32; o > 0; o >>= 1) v += __shfl_down(v, o, 64);
  int tid = threadIdx.x;
  int wid = tid >> 6, nw = blockDim.x >> 6;
  __syncthreads();                      // protect sc from previous use
  if ((tid & 63) == 0) sc[wid] = v;
  __syncthreads();
  float s = 0.f;
  for (int w = 0; w < nw; ++w) s += sc[w];
  return s;
}

// ---------------- weight prep: fp32 [K,N] -> bf16 [N,K] ---------------------
__global__ __launch_bounds__(256) void prep_w(
    const float* __restrict__ Wg0, const float* __restrict__ Wc0,
    const float* __restrict__ Wg1, const float* __restrict__ Wc1,
    const float* __restrict__ Wq, const float* __restrict__ Wk,
    const float* __restrict__ Wv, const float* __restrict__ Wo,
    __hip_bfloat16* __restrict__ Wt) {
  int seg = blockIdx.y;
  const float* W; int N, K; size_t off;
  switch (seg) {
    case 0: W = Wg0; N = 512; K = 256; off = 0;      break;
    case 1: W = Wc0; N = 256; K = 256; off = 131072; break;
    case 2: W = Wg1; N = 512; K = 256; off = 196608; break;
    case 3: W = Wc1; N = 256; K = 256; off = 327680; break;
    case 4: W = Wq;  N = 64;  K = 256; off = 393216; break;
    case 5: W = Wk;  N = 64;  K = 256; off = 409600; break;
    case 6: W = Wv;  N = 64;  K = 256; off = 425984; break;
    default: W = Wo; N = 256; K = 64;  off = 442368; break;
  }
  int total = N * K;
  for (int i = blockIdx.x * 256 + threadIdx.x; i < total; i += 128 * 256) {
    int n = i / K, k = i - n * K;
    Wt[off + (size_t)n * K + k] = __float2bfloat16(W[(size_t)k * N + n]);
  }
}

// ---------------- input projection + LN0: one block per token, 256 thr -------
__global__ __launch_bounds__(256) void inproj_ln(
    const float* __restrict__ xc, const float* __restrict__ Wi,
    const float* __restrict__ bi, const float* __restrict__ sc_,
    const float* __restrict__ bb, float* __restrict__ X) {
  __shared__ float sc[8];
  int tok = blockIdx.x, j = threadIdx.x;
  const float* xr = xc + tok * FC;
  float acc = bi[j];
  #pragma unroll
  for (int i = 0; i < FC; ++i) acc += xr[i] * Wi[i * D_ + j];
  float m = blk_sum(acc, sc) * (1.f / D_);
  float d = acc - m;
  float var = blk_sum(d * d, sc) * (1.f / D_);
  X[tok * D_ + j] = d * rsqrtf(var + EPS) * sc_[j] + bb[j];
}

// ---------------- LN over D=256 per token, residual add ---------------------
__global__ __launch_bounds__(256) void ln_token_res(
    const float* __restrict__ in, const float* __restrict__ sc_,
    const float* __restrict__ bb, const float* __restrict__ resid,
    float* __restrict__ out) {
  __shared__ float sc[8];
  int tok = blockIdx.x, j = threadIdx.x;
  float v = in[tok * D_ + j];
  float m = blk_sum(v, sc) * (1.f / D_);
  float d = v - m;
  float var = blk_sum(d * d, sc) * (1.f / D_);
  out[tok * D_ + j] = d * rsqrtf(var + EPS) * sc_[j] + bb[j] + resid[tok * D_ + j];
}

// ---------------- fused LN2(+res into X) then LN_attn -> O (bf16) -----------
__global__ __launch_bounds__(256) void ln_ln(
    const float* __restrict__ Y, const float* __restrict__ s2,
    const float* __restrict__ b2, float* __restrict__ X,
    const float* __restrict__ sa, const float* __restrict__ ba,
    __hip_bfloat16* __restrict__ O) {
  __shared__ float sc[8];
  int tok = blockIdx.x, j = threadIdx.x;
  float v = Y[tok * D_ + j];
  float m = blk_sum(v, sc) * (1.f / D_);
  float d = v - m;
  float var = blk_sum(d * d, sc) * (1.f / D_);
  float r = d * rsqrtf(var + EPS) * s2[j] + b2[j] + X[tok * D_ + j];
  X[tok * D_ + j] = r;
  float m2 = blk_sum(r, sc) * (1.f / D_);
  float d2 = r - m2;
  float var2 = blk_sum(d2 * d2, sc) * (1.f / D_);
  O[tok * D_ + j] = __float2bfloat16(d2 * rsqrtf(var2 + EPS) * sa[j] + ba[j]);
}

// ---------------- bf16 MFMA GEMM body: BK=64, reg dbuf, bf16 [N,K] W --------
template <int BN, typename AT, int OBF>
__device__ __forceinline__ void gemm_body(
    const AT* __restrict__ A, const __hip_bfloat16* __restrict__ Wt,
    const float* __restrict__ bias, const float* __restrict__ resid,
    void* __restrict__ OUTv, int N, int bn0, int K, int act, int res,
    short* As, short* Bs) {
  constexpr int BT = BN / 32;           // B bf16x8 tasks per thread
  constexpr int NT16 = BN / 16;         // n-tiles per wave
  int tid = threadIdx.x;
  int wave = tid >> 6, lane = tid & 63;
  int quad = lane >> 4, m16 = lane & 15;
  int row0 = blockIdx.x * 128;
  const AT* Ag = A + (size_t)row0 * K;
  const __hip_bfloat16* Wg = Wt + (size_t)bn0 * K;

  f32x4 acc[2][NT16];
  #pragma unroll
  for (int mt = 0; mt < 2; ++mt)
    #pragma unroll
    for (int nt = 0; nt < NT16; ++nt) acc[mt][nt] = (f32x4){0.f, 0.f, 0.f, 0.f};

  float aRf[4][8];                      // fp32 A staging regs
  bf16x8 aRb[4];                        // bf16 A staging regs
  bf16x8 bRb[BT];                       // bf16 B staging regs

  auto loadA = [&](int kk) {
    #pragma unroll
    for (int i = 0; i < 4; ++i) {
      int idx = tid + i * 256;
      int r = idx >> 3, oct = idx & 7;
      if constexpr (sizeof(AT) == 4) {
        const float* p = (const float*)Ag + (size_t)r * K + kk + oct * 8;
        float4 x = *(const float4*)p;
        float4 y = *(const float4*)(p + 4);
        aRf[i][0] = x.x; aRf[i][1] = x.y; aRf[i][2] = x.z; aRf[i][3] = x.w;
        aRf[i][4] = y.x; aRf[i][5] = y.y; aRf[i][6] = y.z; aRf[i][7] = y.w;
      } else {
        aRb[i] = *(const bf16x8*)((const __hip_bfloat16*)Ag +
                                  (size_t)r * K + kk + oct * 8);
      }
    }
  };
  auto loadB = [&](int kk) {
    #pragma unroll
    for (int i = 0; i < BT; ++i) {
      int idx = tid + i * 256;
      int n = idx >> 3, oct = idx & 7;
      bRb[i] = *(const bf16x8*)(Wg + (size_t)n * K + kk + oct * 8);
    }
  };
  auto storeA = [&]() {
    #pragma unroll
    for (int i = 0; i < 4; ++i) {
      int idx = tid + i * 256;
      int r = idx >> 3, oct = idx & 7;
      if constexpr (sizeof(AT) == 4) {
        bf16x8 v;
        #pragma unroll
        for (int j = 0; j < 8; ++j) v[j] = f2bf(aRf[i][j]);
        *(bf16x8*)&As[r * 72 + oct * 8] = v;
      } else {
        *(bf16x8*)&As[r * 72 + oct * 8] = aRb[i];
      }
    }
  };
  auto storeB = [&]() {
    #pragma unroll
    for (int i = 0; i < BT; ++i) {
      int idx = tid + i * 256;
      int n = idx >> 3, oct = idx & 7;
      *(bf16x8*)&Bs[n * 72 + oct * 8] = bRb[i];
    }
  };

  loadA(0); loadB(0);
  for (int kk = 0; kk < K; kk += 64) {
    storeA(); storeB();                 // vmcnt wait for staging regs lands here
    __builtin_amdgcn_s_waitcnt(0xC07F); // lgkmcnt(0) only
    __builtin_amdgcn_s_barrier();
    if (kk + 64 < K) { loadA(kk + 64); loadB(kk + 64); }
    #pragma unroll
    for (int kc = 0; kc < 2; ++kc) {
      bf16x8 af0 = *(const bf16x8*)&As[(wave * 32 + m16) * 72 + kc * 32 + quad * 8];
      bf16x8 af1 = *(const bf16x8*)&As[(wave * 32 + 16 + m16) * 72 + kc * 32 + quad * 8];
      #pragma unroll
      for (int nt = 0; nt < NT16; ++nt) {
        bf16x8 bfr = *(const bf16x8*)&Bs[(nt * 16 + m16) * 72 + kc * 32 + quad * 8];
        acc[0][nt] = __builtin_amdgcn_mfma_f32_16x16x32_bf16(af0, bfr, acc[0][nt], 0, 0, 0);
        acc[1][nt] = __builtin_amdgcn_mfma_f32_16x16x32_bf16(af1, bfr, acc[1][nt], 0, 0, 0);
      }
    }
    __builtin_amdgcn_s_waitcnt(0xC07F);
    __builtin_amdgcn_s_barrier();
  }
  // epilogue: C/D layout col=lane&15, row=quad*4+reg
  #pragma unroll
  for (int mt = 0; mt < 2; ++mt) {
    #pragma unroll
    for (int nt = 0; nt < NT16; ++nt) {
      int col = bn0 + nt * 16 + m16;
      float bv = bias[col];
      #pragma unroll
      for (int r = 0; r < 4; ++r) {
        int row = row0 + wave * 32 + mt * 16 + quad * 4 + r;
        float v = acc[mt][nt][r] + bv;
        if (act) v = 1.f / (1.f + __expf(-v));
        if (res) v += resid[(size_t)row * N + col];
        if constexpr (OBF) {
          ((__hip_bfloat16*)OUTv)[(size_t)row * N + col] = __float2bfloat16(v);
        } else {
          ((float*)OUTv)[(size_t)row * N + col] = v;
        }
      }
    }
  }
}

// fused gates+cx. grid (144, 6): y<4 -> G f32 (sigmoid), y>=4 -> C bf16.
__global__ __launch_bounds__(256) void gemm_gru(
    const float* __restrict__ A, const __hip_bfloat16* __restrict__ WtG,
    const float* __restrict__ bg, const __hip_bfloat16* __restrict__ WtC,
    const float* __restrict__ bc, float* __restrict__ G,
    __hip_bfloat16* __restrict__ Cc) {
  __shared__ short As[128 * 72];
  __shared__ short Bs[128 * 72];
  if (blockIdx.y < 4) {
    gemm_body<128, float, 0>(A, WtG, bg, nullptr, (void*)G, 512,
                             blockIdx.y * 128, 256, 1, 0, As, Bs);
  } else {
    gemm_body<128, float, 1>(A, WtC, bc, nullptr, (void*)Cc, 256,
                             (blockIdx.y - 4) * 128, 256, 0, 0, As, Bs);
  }
}

// fused Q/K/V from bf16 A. grid (144, 3).
__global__ __launch_bounds__(256) void gemm_qkv(
    const __hip_bfloat16* __restrict__ A, const __hip_bfloat16* __restrict__ Wtq,
    const float* __restrict__ bq, const __hip_bfloat16* __restrict__ Wtk,
    const float* __restrict__ bk, const __hip_bfloat16* __restrict__ Wtv,
    const float* __restrict__ bv, float* __restrict__ Q,
    float* __restrict__ Kb, float* __restrict__ V) {
  __shared__ short As[128 * 72];
  __shared__ short Bs[64 * 72];
  int y = blockIdx.y;
  const __hip_bfloat16* W = (y == 0) ? Wtq : (y == 1) ? Wtk : Wtv;
  const float* bi = (y == 0) ? bq : (y == 1) ? bk : bv;
  float* O = (y == 0) ? Q : (y == 1) ? Kb : V;
  gemm_body<64, __hip_bfloat16, 0>(A, W, bi, nullptr, O, 64, 0, 256, 0, 0, As, Bs);
}

// attention out-proj (bf16 A) with f32 residual. grid (144, 2). K=64.
__global__ __launch_bounds__(256) void gemm_proj(
    const __hip_bfloat16* __restrict__ A, const __hip_bfloat16* __restrict__ Wto,
    const float* __restrict__ bi, const float* __restrict__ resid,
    float* __restrict__ O) {
  __shared__ short As[128 * 72];
  __shared__ short Bs[128 * 72];
  gemm_body<128, __hip_bfloat16, 0>(A, Wto, bi, resid, O, 256, blockIdx.y * 128,
                                    64, 0, 1, As, Bs);
}

// ---------------- GRU sequential scan v8: 2 batches/block, 1024 thr ---------
// 16 waves = 2 groups of 8; group g handles batch 2*blk+g with its own
// vstage[g]. Inner wave shape identical to R10 (32 cols/wave, 16 MFMA as
// 8 2-deep chains, R7 4-step group prefetch). The ~780cyc per-step serial
// tail is amortized over 2 batch-steps; group tails overlap the other
// group's MFMA phase. Split barrier (lgkmcnt only). G f32, C bf16.
__global__ __launch_bounds__(1024, 4) void gru_scan(
    const float* __restrict__ G, const __hip_bfloat16* __restrict__ C,
    const float* __restrict__ Wch, const float* __restrict__ bch,
    float* __restrict__ Y) {
  __shared__ short vstage[2][2][256];   // [group][buf][col]
  int tid = threadIdx.x;
  int wv = tid >> 6;                    // 0..15
  int grp = wv >> 3;                    // 0..1
  int wave = wv & 7;                    // wave within group
  int lane = tid & 63;
  int quad = lane >> 4, m16 = lane & 15;
  int col0 = 32 * wave + m16;           // tile 2w
  int col1 = col0 + 16;                 // tile 2w+1
  int b = 2 * blockIdx.x + grp;

  // one-time Wch fragment preload: B-frag[k=32c+quad*8+j][n=col]
  bf16x8 wfrag[2][8];
  #pragma unroll
  for (int tt = 0; tt < 2; ++tt) {
    int n = (tt == 0) ? col0 : col1;
    #pragma unroll
    for (int c = 0; c < 8; ++c) {
      const float* wp = Wch + (size_t)(32 * c + quad * 8) * D_ + n;
      bf16x8 w;
      #pragma unroll
      for (int j = 0; j < 8; ++j) w[j] = f2bf(wp[(size_t)j * D_]);
      wfrag[tt][c] = w;
    }
  }

  const float* Gp = G + (size_t)b * S_ * 512;
  const __hip_bfloat16* Cp = C + (size_t)b * S_ * 256;
  float* Yp = Y + (size_t)b * S_ * 256;

  float bch0 = bch[col0], bch1 = bch[col1];
  float h0 = 0.f, h1 = 0.f;

  float cu0[4], cu1[4], cc0[4], cc1[4], cr0[4], cr1[4];
  #pragma unroll
  for (int i = 0; i < 4; ++i) {
    cu0[i] = Gp[(size_t)i * 512 + 256 + col0];
    cu1[i] = Gp[(size_t)i * 512 + 256 + col1];
    cc0[i] = b2f(Cp[(size_t)i * 256 + col0]);
    cc1[i] = b2f(Cp[(size_t)i * 256 + col1]);
    cr0[i] = Gp[(size_t)(i + 1) * 512 + col0];
    cr1[i] = Gp[(size_t)(i + 1) * 512 + col1];
  }

  if ((tid & 511) < 256) vstage[grp][0][tid & 255] = 0;  // v_0 = 0
  __syncthreads();

  constexpr int NGRP = S_ / 4;          // 72
  for (int g = 0; g < NGRP; ++g) {
    int gn = (g + 1 < NGRP) ? g + 1 : NGRP - 1;
    const float* Gn = Gp + (size_t)gn * 4 * 512;
    const __hip_bfloat16* Cn = Cp + (size_t)gn * 4 * 256;
    float nu0[4], nu1[4], nc0[4], nc1[4], nr0[4], nr1[4];
    #pragma unroll
    for (int i = 0; i < 4; ++i) {
      nu0[i] = Gn[(size_t)i * 512 + 256 + col0];
      nu1[i] = Gn[(size_t)i * 512 + 256 + col1];
      nc0[i] = b2f(Cn[(size_t)i * 256 + col0]);
      nc1[i] = b2f(Cn[(size_t)i * 256 + col1]);
      int ri = (gn * 4 + i + 1 < S_) ? i + 1 : i;
      nr0[i] = Gn[(size_t)ri * 512 + col0];
      nr1[i] = Gn[(size_t)ri * 512 + col1];
    }
    #pragma unroll
    for (int i = 0; i < 4; ++i) {
      int t = g * 4 + i;
      int buf = t & 1;
      f32x4 A0[4], A1[4];
      #pragma unroll
      for (int j = 0; j < 4; ++j) {
        A0[j] = (f32x4){0.f, 0.f, 0.f, 0.f};
        A1[j] = (f32x4){0.f, 0.f, 0.f, 0.f};
      }
      #pragma unroll
      for (int p = 0; p < 2; ++p) {
        #pragma unroll
        for (int j = 0; j < 4; ++j) {
          int c = p * 4 + j;
          bf16x8 af = *(const bf16x8*)&vstage[grp][buf][(c * 4 + quad) * 8];
          A0[j] = __builtin_amdgcn_mfma_f32_16x16x32_bf16(af, wfrag[0][c], A0[j], 0, 0, 0);
          A1[j] = __builtin_amdgcn_mfma_f32_16x16x32_bf16(af, wfrag[1][c], A1[j], 0, 0, 0);
        }
      }
      float s0 = cc0[i] + bch0 + ((A0[0][0] + A0[1][0]) + (A0[2][0] + A0[3][0]));
      float s1 = cc1[i] + bch1 + ((A1[0][0] + A1[1][0]) + (A1[2][0] + A1[3][0]));
      float e0 = __expf(2.f * s0), e1 = __expf(2.f * s1);
      float cand0 = 1.f - 2.f / (e0 + 1.f);
      float cand1 = 1.f - 2.f / (e1 + 1.f);
      h0 = cu0[i] * h0 + (1.f - cu0[i]) * cand0;
      h1 = cu1[i] * h1 + (1.f - cu1[i]) * cand1;
      short v0 = f2bf(cr0[i] * h0), v1 = f2bf(cr1[i] * h1);
      if (quad == 0) {
        Yp[(size_t)t * 256 + col0] = h0;
        Yp[(size_t)t * 256 + col1] = h1;
        vstage[grp][buf ^ 1][col0] = v0; // safe: buf^1 reads done at t-1
        vstage[grp][buf ^ 1][col1] = v1;
      }
      __builtin_amdgcn_s_waitcnt(0xC07F);  // lgkmcnt(0) only
      __builtin_amdgcn_s_barrier();
    }
    #pragma unroll
    for (int i = 0; i < 4; ++i) {
      cu0[i] = nu0[i]; cu1[i] = nu1[i];
      cc0[i] = nc0[i]; cc1[i] = nc1[i];
      cr0[i] = nr0[i]; cr1[i] = nr1[i];
    }
  }
}

// ---------------- flash attention: block=(b,head), 320 thr, K/V in LDS -------
// AO written as bf16.
__global__ __launch_bounds__(320) void attn(
    const float* __restrict__ Q, const float* __restrict__ Kv,
    const float* __restrict__ V, __hip_bfloat16* __restrict__ AO) {
  __shared__ float Kl[S_ * HD];
  __shared__ float Vl[S_ * HD];
  int b = blockIdx.x, hh = blockIdx.y;
  int tid = threadIdx.x;
  int hoff = hh * HD;
  for (int idx = tid; idx < S_ * HD; idx += 320) {
    int row = idx >> 4, d = idx & 15;
    Kl[idx] = Kv[((size_t)(b * S_ + row)) * QKVN + hoff + d];
    Vl[idx] = V[((size_t)(b * S_ + row)) * QKVN + hoff + d];
  }
  __syncthreads();
  if (tid >= S_) return;
  const float* qp = Q + ((size_t)(b * S_ + tid)) * QKVN + hoff;
  float4 q0 = *(const float4*)(qp + 0);
  float4 q1 = *(const float4*)(qp + 4);
  float4 q2 = *(const float4*)(qp + 8);
  float4 q3 = *(const float4*)(qp + 12);
  float m = -1e30f, l = 0.f;
  float4 o0 = {0, 0, 0, 0}, o1 = {0, 0, 0, 0}, o2 = {0, 0, 0, 0},
         o3 = {0, 0, 0, 0};
  for (int k = 0; k < S_; ++k) {
    const float4* kp = (const float4*)&Kl[k * HD];
    float4 k0 = kp[0], k1 = kp[1], k2 = kp[2], k3 = kp[3];
    float s = q0.x * k0.x + q0.y * k0.y + q0.z * k0.z + q0.w * k0.w +
              q1.x * k1.x + q1.y * k1.y + q1.z * k1.z + q1.w * k1.w +
              q2.x * k2.x + q2.y * k2.y + q2.z * k2.z + q2.w * k2.w +
              q3.x * k3.x + q3.y * k3.y + q3.z * k3.z + q3.w * k3.w;
    s *= 0.25f;                          // 1/sqrt(16)
    float mn = fmaxf(m, s);
    float corr = __expf(m - mn);
    float p = __expf(s - mn);
    l = l * corr + p;
    const float4* vp = (const float4*)&Vl[k * HD];
    float4 v0 = vp[0], v1 = vp[1], v2 = vp[2], v3 = vp[3];
    o0.x = o0.x * corr + p * v0.x; o0.y = o0.y * corr + p * v0.y;
    o0.z = o0.z * corr + p * v0.z; o0.w = o0.w * corr + p * v0.w;
    o1.x = o1.x * corr + p * v1.x; o1.y = o1.y * corr + p * v1.y;
    o1.z = o1.z * corr + p * v1.z; o1.w = o1.w * corr + p * v1.w;
    o2.x = o2.x * corr + p * v2.x; o2.y = o2.y * corr + p * v2.y;
    o2.z = o2.z * corr + p * v2.z; o2.w = o2.w * corr + p * v2.w;
    o3.x = o3.x * corr + p * v3.x; o3.y = o3.y * corr + p * v3.y;
    o3.z = o3.z * corr + p * v3.z; o3.w = o3.w * corr + p * v3.w;
    m = mn;
  }
  float inv = 1.f / l;
  __hip_bfloat16* op = AO + ((size_t)(b * S_ + tid)) * QKVN + hoff;
  bf16x8 w0, w1;
  w0[0] = f2bf(o0.x * inv); w0[1] = f2bf(o0.y * inv);
  w0[2] = f2bf(o0.z * inv); w0[3] = f2bf(o0.w * inv);
  w0[4] = f2bf(o1.x * inv); w0[5] = f2bf(o1.y * inv);
  w0[6] = f2bf(o1.z * inv); w0[7] = f2bf(o1.w * inv);
  w1[0] = f2bf(o2.x * inv); w1[1] = f2bf(o2.y * inv);
  w1[2] = f2bf(o2.z * inv); w1[3] = f2bf(o2.w * inv);
  w1[4] = f2bf(o3.x * inv); w1[5] = f2bf(o3.y * inv);
  w1[6] = f2bf(o3.z * inv); w1[7] = f2bf(o3.w * inv);
  *(bf16x8*)op = w0;
  *(bf16x8*)(op + 8) = w1;
}

// ---------------- head: pool + concat + d1(LN) + d2(LN) + out ----------------
__global__ __launch_bounds__(256) void head(
    const float* __restrict__ X, const float* __restrict__ xo,
    const float* __restrict__ Wd1, const float* __restrict__ bd1,
    const float* __restrict__ s1, const float* __restrict__ b1,
    const float* __restrict__ Wd2, const float* __restrict__ bd2,
    const float* __restrict__ s2, const float* __restrict__ b2,
    const float* __restrict__ Wout, const float* __restrict__ bout,
    float* __restrict__ out) {
  __shared__ float c[D_ + FO];
  __shared__ float h1[128];
  __shared__ float sc[8];
  int b = blockIdx.x, tid = threadIdx.x;
  {
    float acc = 0.f;
    const float* xp = X + (size_t)b * S_ * D_ + tid;
    #pragma unroll 4
    for (int t = 0; t < S_; ++t) acc += xp[(size_t)t * D_];
    c[tid] = acc * (1.f / S_);
  }
  if (tid < FO) c[D_ + tid] = xo[b * FO + tid];
  __syncthreads();
  // dense1 (128 outputs) + relu + LN
  float v = 0.f;
  if (tid < 128) {
    v = bd1[tid];
    for (int k = 0; k < D_ + FO; ++k) v += c[k] * Wd1[k * 128 + tid];
    v = fmaxf(v, 0.f);
  }
  float m = blk_sum(tid < 128 ? v : 0.f, sc) * (1.f / 128.f);
  float d = v - m;
  float var = blk_sum(tid < 128 ? d * d : 0.f, sc) * (1.f / 128.f);
  if (tid < 128) h1[tid] = d * rsqrtf(var + EPS) * s1[tid] + b1[tid];
  __syncthreads();
  // dense2 (64 outputs) + relu + LN
  float v2 = 0.f;
  if (tid < 64) {
    v2 = bd2[tid];
    for (int k = 0; k < 128; ++k) v2 += h1[k] * Wd2[k * 64 + tid];
    v2 = fmaxf(v2, 0.f);
  }
  float m2 = blk_sum(tid < 64 ? v2 : 0.f, sc) * (1.f / 64.f);
  float d2v = v2 - m2;
  float var2 = blk_sum(tid < 64 ? d2v * d2v : 0.f, sc) * (1.f / 64.f);
  float hv = (tid < 64) ? (d2v * rsqrtf(var2 + EPS) * s2[tid] + b2[tid]) : 0.f;
  float p = (tid < 64) ? hv * Wout[tid] : 0.f;
  float tot = blk_sum(p, sc);
  if (tid == 0) out[b] = tot + bout[0];
}

extern "C" void kernel_launch(void* const* d_in, const int* in_sizes, int n_in,
                              void* d_out, int out_size, void* d_ws,
                              size_t ws_size, hipStream_t stream) {
  const float* x_cgm = (const float*)d_in[0];
  const float* x_other = (const float*)d_in[1];
  const float* W_in = (const float*)d_in[2];
  const float* b_in = (const float*)d_in[3];
  const float* ln0_s = (const float*)d_in[4];
  const float* ln0_b = (const float*)d_in[5];
  const float* g0_Wg = (const float*)d_in[6];
  const float* g0_bg = (const float*)d_in[7];
  const float* g0_Wcx = (const float*)d_in[8];
  const float* g0_bcx = (const float*)d_in[9];
  const float* g0_Wch = (const float*)d_in[10];
  const float* g0_bch = (const float*)d_in[11];
  const float* g1_Wg = (const float*)d_in[12];
  const float* g1_bg = (const float*)d_in[13];
  const float* g1_Wcx = (const float*)d_in[14];
  const float* g1_bcx = (const float*)d_in[15];
  const float* g1_Wch = (const float*)d_in[16];
  const float* g1_bch = (const float*)d_in[17];
  const float* ln1_s = (const float*)d_in[18];
  const float* ln1_b = (const float*)d_in[19];
  const float* ln2_s = (const float*)d_in[20];
  const float* ln2_b = (const float*)d_in[21];
  const float* aln_s = (const float*)d_in[22];
  const float* aln_b = (const float*)d_in[23];
  const float* Wq = (const float*)d_in[24];
  const float* Wk = (const float*)d_in[25];
  const float* Wv = (const float*)d_in[26];
  const float* bq = (const float*)d_in[27];
  const float* bk = (const float*)d_in[28];
  const float* bv = (const float*)d_in[29];
  const float* Wo = (const float*)d_in[30];
  const float* bo = (const float*)d_in[31];
  const float* Wd1 = (const float*)d_in[32];
  const float* bd1 = (const float*)d_in[33];
  const float* lnd1_s = (const float*)d_in[34];
  const float* lnd1_b = (const float*)d_in[35];
  const float* Wd2 = (const float*)d_in[36];
  const float* bd2 = (const float*)d_in[37];
  const float* lnd2_s = (const float*)d_in[38];
  const float* lnd2_b = (const float*)d_in[39];
  const float* Wout = (const float*)d_in[40];
  const float* bout = (const float*)d_in[41];
  (void)in_sizes; (void)n_in; (void)out_size; (void)ws_size;

  float* ws = (float*)d_ws;
  float* X = ws;                                       // f32 [TOK,256]
  float* Yb = ws + NX;                                 // f32 [TOK,256]
  float* Gb = ws + 2 * NX;                             // f32 [TOK,512]
  __hip_bfloat16* Cb = (__hip_bfloat16*)(ws + 2 * NX + NG); // bf16 [TOK,256]
  __hip_bfloat16* Wt = (__hip_bfloat16*)(ws + 2 * NX + NG + NX / 2);
  // attention-phase reuse:
  float* Qb = Gb;                                      // f32 [TOK,64]
  float* Kbuf = Qb + TOK * QKVN;
  float* Vbuf = Qb + 2 * TOK * QKVN;
  __hip_bfloat16* Obuf = Cb;                           // bf16 ln-attn out
  __hip_bfloat16* AO = (__hip_bfloat16*)Yb;            // bf16 attn out

  // Wt segment offsets (shorts)
  __hip_bfloat16* Wt_g0 = Wt + 0;
  __hip_bfloat16* Wt_c0 = Wt + 131072;
  __hip_bfloat16* Wt_g1 = Wt + 196608;
  __hip_bfloat16* Wt_c1 = Wt + 327680;
  __hip_bfloat16* Wt_q  = Wt + 393216;
  __hip_bfloat16* Wt_k  = Wt + 409600;
  __hip_bfloat16* Wt_v  = Wt + 425984;
  __hip_bfloat16* Wt_o  = Wt + 442368;

  const int MB = TOK / 128;     // 144

  prep_w<<<dim3(128, 8), 256, 0, stream>>>(g0_Wg, g0_Wcx, g1_Wg, g1_Wcx,
                                           Wq, Wk, Wv, Wo, Wt);
  inproj_ln<<<TOK, 256, 0, stream>>>(x_cgm, W_in, b_in, ln0_s, ln0_b, X);

  // GRU block 0
  gemm_gru<<<dim3(MB, 6), 256, 0, stream>>>(X, Wt_g0, g0_bg, Wt_c0, g0_bcx, Gb, Cb);
  gru_scan<<<B_ / 2, 1024, 0, stream>>>(Gb, Cb, g0_Wch, g0_bch, Yb);
  ln_token_res<<<TOK, 256, 0, stream>>>(Yb, ln1_s, ln1_b, X, X);

  // GRU block 1
  gemm_gru<<<dim3(MB, 6), 256, 0, stream>>>(X, Wt_g1, g1_bg, Wt_c1, g1_bcx, Gb, Cb);
  gru_scan<<<B_ / 2, 1024, 0, stream>>>(Gb, Cb, g1_Wch, g1_bch, Yb);

  // fused LN2(+res) and attention-LN -> Obuf (bf16; C dead)
  ln_ln<<<TOK, 256, 0, stream>>>(Yb, ln2_s, ln2_b, X, aln_s, aln_b, Obuf);

  // attention
  gemm_qkv<<<dim3(MB, 3), 256, 0, stream>>>(Obuf, Wt_q, bq, Wt_k, bk, Wt_v, bv,
                                            Qb, Kbuf, Vbuf);
  attn<<<dim3(B_, 4), 320, 0, stream>>>(Qb, Kbuf, Vbuf, AO);
  gemm_proj<<<dim3(MB, 2), 256, 0, stream>>>(AO, Wt_o, bo, X, X);

  // head
  head<<<B_, 256, 0, stream>>>(X, x_other, Wd1, bd1, lnd1_s, lnd1_b,
                               Wd2, bd2, lnd2_s, lnd2_b, Wout, bout,
                               (float*)d_out);
}

// Round 13
// 696.808 us; speedup vs baseline: 2.8680x; 2.8680x over previous
//
#include <hip/hip_runtime.h>
#include <hip/hip_bf16.h>
#include <math.h>

// GRUModel: B=64,S=288,Fc=16,Fo=32,D=256,QKV=64,HEADS=4,hd=16
// Round 13: full revert to R10 (best measured: 700us). R12's 2-batch scan
// spilled wfrag to scratch (launch_bounds(1024,4) caps VGPR < 64+needed;
// WRITE_SIZE +9.4MB spill traffic, 822us). R10 scan: 8 waves x 32 cols,
// W-in-VGPR (84 VGPR), split barrier, 4-step group prefetch, G f32 C bf16.
// ws layout (floats): X[NX] | Yb[NX] | G f32[NG] | C bf16[NX/2] | Wt[229K]

#define EPS 1e-5f
constexpr int B_ = 64, S_ = 288, FC = 16, FO = 32, D_ = 256, QKVN = 64, HD = 16;
constexpr int TOK = B_ * S_;            // 18432
constexpr int NX = TOK * D_;            // 4718592
constexpr int NG = TOK * 512;           // 9437184

typedef short bf16x8 __attribute__((ext_vector_type(8)));
typedef float f32x4 __attribute__((ext_vector_type(4)));

__device__ __forceinline__ short f2bf(float f) {
  __hip_bfloat16 h = __float2bfloat16(f);
  return __builtin_bit_cast(short, h);
}
__device__ __forceinline__ float b2f(__hip_bfloat16 h) {
  return __bfloat162float(h);
}

// block-wide sum; blockDim multiple of 64, <=512. sc: >= blockDim/64 floats.
__device__ __forceinline__ float blk_sum(float v, float* sc) {
  #pragma unroll
  for (int o = 32; o > 0; o >>= 1) v += __shfl_down(v, o, 64);
  int tid = threadIdx.x;
  int wid = tid >> 6, nw = blockDim.x >> 6;
  __syncthreads();                      // protect sc from previous use
  if ((tid & 63) == 0) sc[wid] = v;
  __syncthreads();
  float s = 0.f;
  for (int w = 0; w < nw; ++w) s += sc[w];
  return s;
}

// ---------------- weight prep: fp32 [K,N] -> bf16 [N,K] ---------------------
__global__ __launch_bounds__(256) void prep_w(
    const float* __restrict__ Wg0, const float* __restrict__ Wc0,
    const float* __restrict__ Wg1, const float* __restrict__ Wc1,
    const float* __restrict__ Wq, const float* __restrict__ Wk,
    const float* __restrict__ Wv, const float* __restrict__ Wo,
    __hip_bfloat16* __restrict__ Wt) {
  int seg = blockIdx.y;
  const float* W; int N, K; size_t off;
  switch (seg) {
    case 0: W = Wg0; N = 512; K = 256; off = 0;      break;
    case 1: W = Wc0; N = 256; K = 256; off = 131072; break;
    case 2: W = Wg1; N = 512; K = 256; off = 196608; break;
    case 3: W = Wc1; N = 256; K = 256; off = 327680; break;
    case 4: W = Wq;  N = 64;  K = 256; off = 393216; break;
    case 5: W = Wk;  N = 64;  K = 256; off = 409600; break;
    case 6: W = Wv;  N = 64;  K = 256; off = 425984; break;
    default: W = Wo; N = 256; K = 64;  off = 442368; break;
  }
  int total = N * K;
  for (int i = blockIdx.x * 256 + threadIdx.x; i < total; i += 128 * 256) {
    int n = i / K, k = i - n * K;
    Wt[off + (size_t)n * K + k] = __float2bfloat16(W[(size_t)k * N + n]);
  }
}

// ---------------- input projection + LN0: one block per token, 256 thr -------
__global__ __launch_bounds__(256) void inproj_ln(
    const float* __restrict__ xc, const float* __restrict__ Wi,
    const float* __restrict__ bi, const float* __restrict__ sc_,
    const float* __restrict__ bb, float* __restrict__ X) {
  __shared__ float sc[8];
  int tok = blockIdx.x, j = threadIdx.x;
  const float* xr = xc + tok * FC;
  float acc = bi[j];
  #pragma unroll
  for (int i = 0; i < FC; ++i) acc += xr[i] * Wi[i * D_ + j];
  float m = blk_sum(acc, sc) * (1.f / D_);
  float d = acc - m;
  float var = blk_sum(d * d, sc) * (1.f / D_);
  X[tok * D_ + j] = d * rsqrtf(var + EPS) * sc_[j] + bb[j];
}

// ---------------- LN over D=256 per token, residual add ---------------------
__global__ __launch_bounds__(256) void ln_token_res(
    const float* __restrict__ in, const float* __restrict__ sc_,
    const float* __restrict__ bb, const float* __restrict__ resid,
    float* __restrict__ out) {
  __shared__ float sc[8];
  int tok = blockIdx.x, j = threadIdx.x;
  float v = in[tok * D_ + j];
  float m = blk_sum(v, sc) * (1.f / D_);
  float d = v - m;
  float var = blk_sum(d * d, sc) * (1.f / D_);
  out[tok * D_ + j] = d * rsqrtf(var + EPS) * sc_[j] + bb[j] + resid[tok * D_ + j];
}

// ---------------- fused LN2(+res into X) then LN_attn -> O (bf16) -----------
__global__ __launch_bounds__(256) void ln_ln(
    const float* __restrict__ Y, const float* __restrict__ s2,
    const float* __restrict__ b2, float* __restrict__ X,
    const float* __restrict__ sa, const float* __restrict__ ba,
    __hip_bfloat16* __restrict__ O) {
  __shared__ float sc[8];
  int tok = blockIdx.x, j = threadIdx.x;
  float v = Y[tok * D_ + j];
  float m = blk_sum(v, sc) * (1.f / D_);
  float d = v - m;
  float var = blk_sum(d * d, sc) * (1.f / D_);
  float r = d * rsqrtf(var + EPS) * s2[j] + b2[j] + X[tok * D_ + j];
  X[tok * D_ + j] = r;
  float m2 = blk_sum(r, sc) * (1.f / D_);
  float d2 = r - m2;
  float var2 = blk_sum(d2 * d2, sc) * (1.f / D_);
  O[tok * D_ + j] = __float2bfloat16(d2 * rsqrtf(var2 + EPS) * sa[j] + ba[j]);
}

// ---------------- bf16 MFMA GEMM body: BK=64, reg dbuf, bf16 [N,K] W --------
template <int BN, typename AT, int OBF>
__device__ __forceinline__ void gemm_body(
    const AT* __restrict__ A, const __hip_bfloat16* __restrict__ Wt,
    const float* __restrict__ bias, const float* __restrict__ resid,
    void* __restrict__ OUTv, int N, int bn0, int K, int act, int res,
    short* As, short* Bs) {
  constexpr int BT = BN / 32;           // B bf16x8 tasks per thread
  constexpr int NT16 = BN / 16;         // n-tiles per wave
  int tid = threadIdx.x;
  int wave = tid >> 6, lane = tid & 63;
  int quad = lane >> 4, m16 = lane & 15;
  int row0 = blockIdx.x * 128;
  const AT* Ag = A + (size_t)row0 * K;
  const __hip_bfloat16* Wg = Wt + (size_t)bn0 * K;

  f32x4 acc[2][NT16];
  #pragma unroll
  for (int mt = 0; mt < 2; ++mt)
    #pragma unroll
    for (int nt = 0; nt < NT16; ++nt) acc[mt][nt] = (f32x4){0.f, 0.f, 0.f, 0.f};

  float aRf[4][8];                      // fp32 A staging regs
  bf16x8 aRb[4];                        // bf16 A staging regs
  bf16x8 bRb[BT];                       // bf16 B staging regs

  auto loadA = [&](int kk) {
    #pragma unroll
    for (int i = 0; i < 4; ++i) {
      int idx = tid + i * 256;
      int r = idx >> 3, oct = idx & 7;
      if constexpr (sizeof(AT) == 4) {
        const float* p = (const float*)Ag + (size_t)r * K + kk + oct * 8;
        float4 x = *(const float4*)p;
        float4 y = *(const float4*)(p + 4);
        aRf[i][0] = x.x; aRf[i][1] = x.y; aRf[i][2] = x.z; aRf[i][3] = x.w;
        aRf[i][4] = y.x; aRf[i][5] = y.y; aRf[i][6] = y.z; aRf[i][7] = y.w;
      } else {
        aRb[i] = *(const bf16x8*)((const __hip_bfloat16*)Ag +
                                  (size_t)r * K + kk + oct * 8);
      }
    }
  };
  auto loadB = [&](int kk) {
    #pragma unroll
    for (int i = 0; i < BT; ++i) {
      int idx = tid + i * 256;
      int n = idx >> 3, oct = idx & 7;
      bRb[i] = *(const bf16x8*)(Wg + (size_t)n * K + kk + oct * 8);
    }
  };
  auto storeA = [&]() {
    #pragma unroll
    for (int i = 0; i < 4; ++i) {
      int idx = tid + i * 256;
      int r = idx >> 3, oct = idx & 7;
      if constexpr (sizeof(AT) == 4) {
        bf16x8 v;
        #pragma unroll
        for (int j = 0; j < 8; ++j) v[j] = f2bf(aRf[i][j]);
        *(bf16x8*)&As[r * 72 + oct * 8] = v;
      } else {
        *(bf16x8*)&As[r * 72 + oct * 8] = aRb[i];
      }
    }
  };
  auto storeB = [&]() {
    #pragma unroll
    for (int i = 0; i < BT; ++i) {
      int idx = tid + i * 256;
      int n = idx >> 3, oct = idx & 7;
      *(bf16x8*)&Bs[n * 72 + oct * 8] = bRb[i];
    }
  };

  loadA(0); loadB(0);
  for (int kk = 0; kk < K; kk += 64) {
    storeA(); storeB();                 // vmcnt wait for staging regs lands here
    __builtin_amdgcn_s_waitcnt(0xC07F); // lgkmcnt(0) only
    __builtin_amdgcn_s_barrier();
    if (kk + 64 < K) { loadA(kk + 64); loadB(kk + 64); }
    #pragma unroll
    for (int kc = 0; kc < 2; ++kc) {
      bf16x8 af0 = *(const bf16x8*)&As[(wave * 32 + m16) * 72 + kc * 32 + quad * 8];
      bf16x8 af1 = *(const bf16x8*)&As[(wave * 32 + 16 + m16) * 72 + kc * 32 + quad * 8];
      #pragma unroll
      for (int nt = 0; nt < NT16; ++nt) {
        bf16x8 bfr = *(const bf16x8*)&Bs[(nt * 16 + m16) * 72 + kc * 32 + quad * 8];
        acc[0][nt] = __builtin_amdgcn_mfma_f32_16x16x32_bf16(af0, bfr, acc[0][nt], 0, 0, 0);
        acc[1][nt] = __builtin_amdgcn_mfma_f32_16x16x32_bf16(af1, bfr, acc[1][nt], 0, 0, 0);
      }
    }
    __builtin_amdgcn_s_waitcnt(0xC07F);
    __builtin_amdgcn_s_barrier();
  }
  // epilogue: C/D layout col=lane&15, row=quad*4+reg
  #pragma unroll
  for (int mt = 0; mt < 2; ++mt) {
    #pragma unroll
    for (int nt = 0; nt < NT16; ++nt) {
      int col = bn0 + nt * 16 + m16;
      float bv = bias[col];
      #pragma unroll
      for (int r = 0; r < 4; ++r) {
        int row = row0 + wave * 32 + mt * 16 + quad * 4 + r;
        float v = acc[mt][nt][r] + bv;
        if (act) v = 1.f / (1.f + __expf(-v));
        if (res) v += resid[(size_t)row * N + col];
        if constexpr (OBF) {
          ((__hip_bfloat16*)OUTv)[(size_t)row * N + col] = __float2bfloat16(v);
        } else {
          ((float*)OUTv)[(size_t)row * N + col] = v;
        }
      }
    }
  }
}

// fused gates+cx. grid (144, 6): y<4 -> G f32 (sigmoid), y>=4 -> C bf16.
__global__ __launch_bounds__(256) void gemm_gru(
    const float* __restrict__ A, const __hip_bfloat16* __restrict__ WtG,
    const float* __restrict__ bg, const __hip_bfloat16* __restrict__ WtC,
    const float* __restrict__ bc, float* __restrict__ G,
    __hip_bfloat16* __restrict__ Cc) {
  __shared__ short As[128 * 72];
  __shared__ short Bs[128 * 72];
  if (blockIdx.y < 4) {
    gemm_body<128, float, 0>(A, WtG, bg, nullptr, (void*)G, 512,
                             blockIdx.y * 128, 256, 1, 0, As, Bs);
  } else {
    gemm_body<128, float, 1>(A, WtC, bc, nullptr, (void*)Cc, 256,
                             (blockIdx.y - 4) * 128, 256, 0, 0, As, Bs);
  }
}

// fused Q/K/V from bf16 A. grid (144, 3).
__global__ __launch_bounds__(256) void gemm_qkv(
    const __hip_bfloat16* __restrict__ A, const __hip_bfloat16* __restrict__ Wtq,
    const float* __restrict__ bq, const __hip_bfloat16* __restrict__ Wtk,
    const float* __restrict__ bk, const __hip_bfloat16* __restrict__ Wtv,
    const float* __restrict__ bv, float* __restrict__ Q,
    float* __restrict__ Kb, float* __restrict__ V) {
  __shared__ short As[128 * 72];
  __shared__ short Bs[64 * 72];
  int y = blockIdx.y;
  const __hip_bfloat16* W = (y == 0) ? Wtq : (y == 1) ? Wtk : Wtv;
  const float* bi = (y == 0) ? bq : (y == 1) ? bk : bv;
  float* O = (y == 0) ? Q : (y == 1) ? Kb : V;
  gemm_body<64, __hip_bfloat16, 0>(A, W, bi, nullptr, O, 64, 0, 256, 0, 0, As, Bs);
}

// attention out-proj (bf16 A) with f32 residual. grid (144, 2). K=64.
__global__ __launch_bounds__(256) void gemm_proj(
    const __hip_bfloat16* __restrict__ A, const __hip_bfloat16* __restrict__ Wto,
    const float* __restrict__ bi, const float* __restrict__ resid,
    float* __restrict__ O) {
  __shared__ short As[128 * 72];
  __shared__ short Bs[128 * 72];
  gemm_body<128, __hip_bfloat16, 0>(A, Wto, bi, resid, O, 256, blockIdx.y * 128,
                                    64, 0, 1, As, Bs);
}

// ---------------- GRU sequential scan (R7/R10 best-known): G f32, C bf16 ----
__global__ __launch_bounds__(512, 2) void gru_scan(
    const float* __restrict__ G, const __hip_bfloat16* __restrict__ C,
    const float* __restrict__ Wch, const float* __restrict__ bch,
    float* __restrict__ Y) {
  __shared__ short vstage[2][256];
  int tid = threadIdx.x;
  int b = blockIdx.x;
  int wave = tid >> 6, lane = tid & 63;
  int quad = lane >> 4, m16 = lane & 15;
  int col0 = 32 * wave + m16;           // tile 2w
  int col1 = col0 + 16;                 // tile 2w+1

  // one-time Wch fragment preload: B-frag[k=32c+quad*8+j][n=col]
  bf16x8 wfrag[2][8];
  #pragma unroll
  for (int tt = 0; tt < 2; ++tt) {
    int n = (tt == 0) ? col0 : col1;
    #pragma unroll
    for (int c = 0; c < 8; ++c) {
      const float* wp = Wch + (size_t)(32 * c + quad * 8) * D_ + n;
      bf16x8 w;
      #pragma unroll
      for (int j = 0; j < 8; ++j) w[j] = f2bf(wp[(size_t)j * D_]);
      wfrag[tt][c] = w;
    }
  }

  const float* Gp = G + (size_t)b * S_ * 512;
  const __hip_bfloat16* Cp = C + (size_t)b * S_ * 256;
  float* Yp = Y + (size_t)b * S_ * 256;

  float bch0 = bch[col0], bch1 = bch[col1];
  float h0 = 0.f, h1 = 0.f;

  float cu0[4], cu1[4], cc0[4], cc1[4], cr0[4], cr1[4];
  #pragma unroll
  for (int i = 0; i < 4; ++i) {
    cu0[i] = Gp[(size_t)i * 512 + 256 + col0];
    cu1[i] = Gp[(size_t)i * 512 + 256 + col1];
    cc0[i] = b2f(Cp[(size_t)i * 256 + col0]);
    cc1[i] = b2f(Cp[(size_t)i * 256 + col1]);
    cr0[i] = Gp[(size_t)(i + 1) * 512 + col0];
    cr1[i] = Gp[(size_t)(i + 1) * 512 + col1];
  }

  if (tid < 256) vstage[0][tid] = 0;    // v_0 = r_0 * h_{-1} = 0
  __syncthreads();

  constexpr int NGRP = S_ / 4;          // 72
  for (int g = 0; g < NGRP; ++g) {
    int gn = (g + 1 < NGRP) ? g + 1 : NGRP - 1;
    const float* Gn = Gp + (size_t)gn * 4 * 512;
    const __hip_bfloat16* Cn = Cp + (size_t)gn * 4 * 256;
    float nu0[4], nu1[4], nc0[4], nc1[4], nr0[4], nr1[4];
    #pragma unroll
    for (int i = 0; i < 4; ++i) {
      nu0[i] = Gn[(size_t)i * 512 + 256 + col0];
      nu1[i] = Gn[(size_t)i * 512 + 256 + col1];
      nc0[i] = b2f(Cn[(size_t)i * 256 + col0]);
      nc1[i] = b2f(Cn[(size_t)i * 256 + col1]);
      int ri = (gn * 4 + i + 1 < S_) ? i + 1 : i;
      nr0[i] = Gn[(size_t)ri * 512 + col0];
      nr1[i] = Gn[(size_t)ri * 512 + col1];
    }
    #pragma unroll
    for (int i = 0; i < 4; ++i) {
      int t = g * 4 + i;
      int buf = t & 1;
      f32x4 A0[4], A1[4];
      #pragma unroll
      for (int j = 0; j < 4; ++j) {
        A0[j] = (f32x4){0.f, 0.f, 0.f, 0.f};
        A1[j] = (f32x4){0.f, 0.f, 0.f, 0.f};
      }
      #pragma unroll
      for (int p = 0; p < 2; ++p) {
        #pragma unroll
        for (int j = 0; j < 4; ++j) {
          int c = p * 4 + j;
          bf16x8 af = *(const bf16x8*)&vstage[buf][(c * 4 + quad) * 8];
          A0[j] = __builtin_amdgcn_mfma_f32_16x16x32_bf16(af, wfrag[0][c], A0[j], 0, 0, 0);
          A1[j] = __builtin_amdgcn_mfma_f32_16x16x32_bf16(af, wfrag[1][c], A1[j], 0, 0, 0);
        }
      }
      float s0 = cc0[i] + bch0 + ((A0[0][0] + A0[1][0]) + (A0[2][0] + A0[3][0]));
      float s1 = cc1[i] + bch1 + ((A1[0][0] + A1[1][0]) + (A1[2][0] + A1[3][0]));
      float e0 = __expf(2.f * s0), e1 = __expf(2.f * s1);
      float cand0 = 1.f - 2.f / (e0 + 1.f);
      float cand1 = 1.f - 2.f / (e1 + 1.f);
      h0 = cu0[i] * h0 + (1.f - cu0[i]) * cand0;
      h1 = cu1[i] * h1 + (1.f - cu1[i]) * cand1;
      short v0 = f2bf(cr0[i] * h0), v1 = f2bf(cr1[i] * h1);
      if (quad == 0) {
        Yp[(size_t)t * 256 + col0] = h0;
        Yp[(size_t)t * 256 + col1] = h1;
        vstage[buf ^ 1][col0] = v0;
        vstage[buf ^ 1][col1] = v1;
      }
      __builtin_amdgcn_s_waitcnt(0xC07F);  // lgkmcnt(0) only
      __builtin_amdgcn_s_barrier();
    }
    #pragma unroll
    for (int i = 0; i < 4; ++i) {
      cu0[i] = nu0[i]; cu1[i] = nu1[i];
      cc0[i] = nc0[i]; cc1[i] = nc1[i];
      cr0[i] = nr0[i]; cr1[i] = nr1[i];
    }
  }
}

// ---------------- flash attention: block=(b,head), 320 thr, K/V in LDS -------
// AO written as bf16.
__global__ __launch_bounds__(320) void attn(
    const float* __restrict__ Q, const float* __restrict__ Kv,
    const float* __restrict__ V, __hip_bfloat16* __restrict__ AO) {
  __shared__ float Kl[S_ * HD];
  __shared__ float Vl[S_ * HD];
  int b = blockIdx.x, hh = blockIdx.y;
  int tid = threadIdx.x;
  int hoff = hh * HD;
  for (int idx = tid; idx < S_ * HD; idx += 320) {
    int row = idx >> 4, d = idx & 15;
    Kl[idx] = Kv[((size_t)(b * S_ + row)) * QKVN + hoff + d];
    Vl[idx] = V[((size_t)(b * S_ + row)) * QKVN + hoff + d];
  }
  __syncthreads();
  if (tid >= S_) return;
  const float* qp = Q + ((size_t)(b * S_ + tid)) * QKVN + hoff;
  float4 q0 = *(const float4*)(qp + 0);
  float4 q1 = *(const float4*)(qp + 4);
  float4 q2 = *(const float4*)(qp + 8);
  float4 q3 = *(const float4*)(qp + 12);
  float m = -1e30f, l = 0.f;
  float4 o0 = {0, 0, 0, 0}, o1 = {0, 0, 0, 0}, o2 = {0, 0, 0, 0},
         o3 = {0, 0, 0, 0};
  for (int k = 0; k < S_; ++k) {
    const float4* kp = (const float4*)&Kl[k * HD];
    float4 k0 = kp[0], k1 = kp[1], k2 = kp[2], k3 = kp[3];
    float s = q0.x * k0.x + q0.y * k0.y + q0.z * k0.z + q0.w * k0.w +
              q1.x * k1.x + q1.y * k1.y + q1.z * k1.z + q1.w * k1.w +
              q2.x * k2.x + q2.y * k2.y + q2.z * k2.z + q2.w * k2.w +
              q3.x * k3.x + q3.y * k3.y + q3.z * k3.z + q3.w * k3.w;
    s *= 0.25f;                          // 1/sqrt(16)
    float mn = fmaxf(m, s);
    float corr = __expf(m - mn);
    float p = __expf(s - mn);
    l = l * corr + p;
    const float4* vp = (const float4*)&Vl[k * HD];
    float4 v0 = vp[0], v1 = vp[1], v2 = vp[2], v3 = vp[3];
    o0.x = o0.x * corr + p * v0.x; o0.y = o0.y * corr + p * v0.y;
    o0.z = o0.z * corr + p * v0.z; o0.w = o0.w * corr + p * v0.w;
    o1.x = o1.x * corr + p * v1.x; o1.y = o1.y * corr + p * v1.y;
    o1.z = o1.z * corr + p * v1.z; o1.w = o1.w * corr + p * v1.w;
    o2.x = o2.x * corr + p * v2.x; o2.y = o2.y * corr + p * v2.y;
    o2.z = o2.z * corr + p * v2.z; o2.w = o2.w * corr + p * v2.w;
    o3.x = o3.x * corr + p * v3.x; o3.y = o3.y * corr + p * v3.y;
    o3.z = o3.z * corr + p * v3.z; o3.w = o3.w * corr + p * v3.w;
    m = mn;
  }
  float inv = 1.f / l;
  __hip_bfloat16* op = AO + ((size_t)(b * S_ + tid)) * QKVN + hoff;
  bf16x8 w0, w1;
  w0[0] = f2bf(o0.x * inv); w0[1] = f2bf(o0.y * inv);
  w0[2] = f2bf(o0.z * inv); w0[3] = f2bf(o0.w * inv);
  w0[4] = f2bf(o1.x * inv); w0[5] = f2bf(o1.y * inv);
  w0[6] = f2bf(o1.z * inv); w0[7] = f2bf(o1.w * inv);
  w1[0] = f2bf(o2.x * inv); w1[1] = f2bf(o2.y * inv);
  w1[2] = f2bf(o2.z * inv); w1[3] = f2bf(o2.w * inv);
  w1[4] = f2bf(o3.x * inv); w1[5] = f2bf(o3.y * inv);
  w1[6] = f2bf(o3.z * inv); w1[7] = f2bf(o3.w * inv);
  *(bf16x8*)op = w0;
  *(bf16x8*)(op + 8) = w1;
}

// ---------------- head: pool + concat + d1(LN) + d2(LN) + out ----------------
__global__ __launch_bounds__(256) void head(
    const float* __restrict__ X, const float* __restrict__ xo,
    const float* __restrict__ Wd1, const float* __restrict__ bd1,
    const float* __restrict__ s1, const float* __restrict__ b1,
    const float* __restrict__ Wd2, const float* __restrict__ bd2,
    const float* __restrict__ s2, const float* __restrict__ b2,
    const float* __restrict__ Wout, const float* __restrict__ bout,
    float* __restrict__ out) {
  __shared__ float c[D_ + FO];
  __shared__ float h1[128];
  __shared__ float sc[8];
  int b = blockIdx.x, tid = threadIdx.x;
  {
    float acc = 0.f;
    const float* xp = X + (size_t)b * S_ * D_ + tid;
    #pragma unroll 4
    for (int t = 0; t < S_; ++t) acc += xp[(size_t)t * D_];
    c[tid] = acc * (1.f / S_);
  }
  if (tid < FO) c[D_ + tid] = xo[b * FO + tid];
  __syncthreads();
  // dense1 (128 outputs) + relu + LN
  float v = 0.f;
  if (tid < 128) {
    v = bd1[tid];
    for (int k = 0; k < D_ + FO; ++k) v += c[k] * Wd1[k * 128 + tid];
    v = fmaxf(v, 0.f);
  }
  float m = blk_sum(tid < 128 ? v : 0.f, sc) * (1.f / 128.f);
  float d = v - m;
  float var = blk_sum(tid < 128 ? d * d : 0.f, sc) * (1.f / 128.f);
  if (tid < 128) h1[tid] = d * rsqrtf(var + EPS) * s1[tid] + b1[tid];
  __syncthreads();
  // dense2 (64 outputs) + relu + LN
  float v2 = 0.f;
  if (tid < 64) {
    v2 = bd2[tid];
    for (int k = 0; k < 128; ++k) v2 += h1[k] * Wd2[k * 64 + tid];
    v2 = fmaxf(v2, 0.f);
  }
  float m2 = blk_sum(tid < 64 ? v2 : 0.f, sc) * (1.f / 64.f);
  float d2v = v2 - m2;
  float var2 = blk_sum(tid < 64 ? d2v * d2v : 0.f, sc) * (1.f / 64.f);
  float hv = (tid < 64) ? (d2v * rsqrtf(var2 + EPS) * s2[tid] + b2[tid]) : 0.f;
  float p = (tid < 64) ? hv * Wout[tid] : 0.f;
  float tot = blk_sum(p, sc);
  if (tid == 0) out[b] = tot + bout[0];
}

extern "C" void kernel_launch(void* const* d_in, const int* in_sizes, int n_in,
                              void* d_out, int out_size, void* d_ws,
                              size_t ws_size, hipStream_t stream) {
  const float* x_cgm = (const float*)d_in[0];
  const float* x_other = (const float*)d_in[1];
  const float* W_in = (const float*)d_in[2];
  const float* b_in = (const float*)d_in[3];
  const float* ln0_s = (const float*)d_in[4];
  const float* ln0_b = (const float*)d_in[5];
  const float* g0_Wg = (const float*)d_in[6];
  const float* g0_bg = (const float*)d_in[7];
  const float* g0_Wcx = (const float*)d_in[8];
  const float* g0_bcx = (const float*)d_in[9];
  const float* g0_Wch = (const float*)d_in[10];
  const float* g0_bch = (const float*)d_in[11];
  const float* g1_Wg = (const float*)d_in[12];
  const float* g1_bg = (const float*)d_in[13];
  const float* g1_Wcx = (const float*)d_in[14];
  const float* g1_bcx = (const float*)d_in[15];
  const float* g1_Wch = (const float*)d_in[16];
  const float* g1_bch = (const float*)d_in[17];
  const float* ln1_s = (const float*)d_in[18];
  const float* ln1_b = (const float*)d_in[19];
  const float* ln2_s = (const float*)d_in[20];
  const float* ln2_b = (const float*)d_in[21];
  const float* aln_s = (const float*)d_in[22];
  const float* aln_b = (const float*)d_in[23];
  const float* Wq = (const float*)d_in[24];
  const float* Wk = (const float*)d_in[25];
  const float* Wv = (const float*)d_in[26];
  const float* bq = (const float*)d_in[27];
  const float* bk = (const float*)d_in[28];
  const float* bv = (const float*)d_in[29];
  const float* Wo = (const float*)d_in[30];
  const float* bo = (const float*)d_in[31];
  const float* Wd1 = (const float*)d_in[32];
  const float* bd1 = (const float*)d_in[33];
  const float* lnd1_s = (const float*)d_in[34];
  const float* lnd1_b = (const float*)d_in[35];
  const float* Wd2 = (const float*)d_in[36];
  const float* bd2 = (const float*)d_in[37];
  const float* lnd2_s = (const float*)d_in[38];
  const float* lnd2_b = (const float*)d_in[39];
  const float* Wout = (const float*)d_in[40];
  const float* bout = (const float*)d_in[41];
  (void)in_sizes; (void)n_in; (void)out_size; (void)ws_size;

  float* ws = (float*)d_ws;
  float* X = ws;                                       // f32 [TOK,256]
  float* Yb = ws + NX;                                 // f32 [TOK,256]
  float* Gb = ws + 2 * NX;                             // f32 [TOK,512]
  __hip_bfloat16* Cb = (__hip_bfloat16*)(ws + 2 * NX + NG); // bf16 [TOK,256]
  __hip_bfloat16* Wt = (__hip_bfloat16*)(ws + 2 * NX + NG + NX / 2);
  // attention-phase reuse:
  float* Qb = Gb;                                      // f32 [TOK,64]
  float* Kbuf = Qb + TOK * QKVN;
  float* Vbuf = Qb + 2 * TOK * QKVN;
  __hip_bfloat16* Obuf = Cb;                           // bf16 ln-attn out
  __hip_bfloat16* AO = (__hip_bfloat16*)Yb;            // bf16 attn out

  // Wt segment offsets (shorts)
  __hip_bfloat16* Wt_g0 = Wt + 0;
  __hip_bfloat16* Wt_c0 = Wt + 131072;
  __hip_bfloat16* Wt_g1 = Wt + 196608;
  __hip_bfloat16* Wt_c1 = Wt + 327680;
  __hip_bfloat16* Wt_q  = Wt + 393216;
  __hip_bfloat16* Wt_k  = Wt + 409600;
  __hip_bfloat16* Wt_v  = Wt + 425984;
  __hip_bfloat16* Wt_o  = Wt + 442368;

  const int MB = TOK / 128;     // 144

  prep_w<<<dim3(128, 8), 256, 0, stream>>>(g0_Wg, g0_Wcx, g1_Wg, g1_Wcx,
                                           Wq, Wk, Wv, Wo, Wt);
  inproj_ln<<<TOK, 256, 0, stream>>>(x_cgm, W_in, b_in, ln0_s, ln0_b, X);

  // GRU block 0
  gemm_gru<<<dim3(MB, 6), 256, 0, stream>>>(X, Wt_g0, g0_bg, Wt_c0, g0_bcx, Gb, Cb);
  gru_scan<<<B_, 512, 0, stream>>>(Gb, Cb, g0_Wch, g0_bch, Yb);
  ln_token_res<<<TOK, 256, 0, stream>>>(Yb, ln1_s, ln1_b, X, X);

  // GRU block 1
  gemm_gru<<<dim3(MB, 6), 256, 0, stream>>>(X, Wt_g1, g1_bg, Wt_c1, g1_bcx, Gb, Cb);
  gru_scan<<<B_, 512, 0, stream>>>(Gb, Cb, g1_Wch, g1_bch, Yb);

  // fused LN2(+res) and attention-LN -> Obuf (bf16; C dead)
  ln_ln<<<TOK, 256, 0, stream>>>(Yb, ln2_s, ln2_b, X, aln_s, aln_b, Obuf);

  // attention
  gemm_qkv<<<dim3(MB, 3), 256, 0, stream>>>(Obuf, Wt_q, bq, Wt_k, bk, Wt_v, bv,
                                            Qb, Kbuf, Vbuf);
  attn<<<dim3(B_, 4), 320, 0, stream>>>(Qb, Kbuf, Vbuf, AO);
  gemm_proj<<<dim3(MB, 2), 256, 0, stream>>>(AO, Wt_o, bo, X, X);

  // head
  head<<<B_, 256, 0, stream>>>(X, x_other, Wd1, bd1, lnd1_s, lnd1_b,
                               Wd2, bd2, lnd2_s, lnd2_b, Wout, bout,
                               (float*)d_out);
}

// Round 14
// 672.992 us; speedup vs baseline: 2.9695x; 1.0354x over previous
//
#include <hip/hip_runtime.h>
#include <hip/hip_bf16.h>
#include <math.h>

// GRUModel: B=64,S=288,Fc=16,Fo=32,D=256,QKV=64,HEADS=4,hd=16
// Round 14: tail micro-package on top of R13 (best-known 697us):
//  (1) LN kernels -> wave-per-token (4 tok/block, shuffle-reduce, 0 barriers)
//  (2) gemm_body K templated (k-loop fully unrolled; 256/64)
// gru_scan frozen at R10 shape (6 falsified redesigns; ~1400cyc/step is
// structural: ~620 MFMA pipe + ~780 serial recurrence tail).
// ws layout (floats): X[NX] | Yb[NX] | G f32[NG] | C bf16[NX/2] | Wt[229K]

#define EPS 1e-5f
constexpr int B_ = 64, S_ = 288, FC = 16, FO = 32, D_ = 256, QKVN = 64, HD = 16;
constexpr int TOK = B_ * S_;            // 18432
constexpr int NX = TOK * D_;            // 4718592
constexpr int NG = TOK * 512;           // 9437184

typedef short bf16x8 __attribute__((ext_vector_type(8)));
typedef short bf16x4 __attribute__((ext_vector_type(4)));
typedef float f32x4 __attribute__((ext_vector_type(4)));

__device__ __forceinline__ short f2bf(float f) {
  __hip_bfloat16 h = __float2bfloat16(f);
  return __builtin_bit_cast(short, h);
}
__device__ __forceinline__ float b2f(__hip_bfloat16 h) {
  return __bfloat162float(h);
}

// wave-wide sum, result broadcast to all 64 lanes.
__device__ __forceinline__ float wave_sum(float v) {
  #pragma unroll
  for (int o = 32; o > 0; o >>= 1) v += __shfl_down(v, o, 64);
  return __shfl(v, 0, 64);
}

// block-wide sum; blockDim multiple of 64, <=512. sc: >= blockDim/64 floats.
__device__ __forceinline__ float blk_sum(float v, float* sc) {
  #pragma unroll
  for (int o = 32; o > 0; o >>= 1) v += __shfl_down(v, o, 64);
  int tid = threadIdx.x;
  int wid = tid >> 6, nw = blockDim.x >> 6;
  __syncthreads();                      // protect sc from previous use
  if ((tid & 63) == 0) sc[wid] = v;
  __syncthreads();
  float s = 0.f;
  for (int w = 0; w < nw; ++w) s += sc[w];
  return s;
}

// ---------------- weight prep: fp32 [K,N] -> bf16 [N,K] ---------------------
__global__ __launch_bounds__(256) void prep_w(
    const float* __restrict__ Wg0, const float* __restrict__ Wc0,
    const float* __restrict__ Wg1, const float* __restrict__ Wc1,
    const float* __restrict__ Wq, const float* __restrict__ Wk,
    const float* __restrict__ Wv, const float* __restrict__ Wo,
    __hip_bfloat16* __restrict__ Wt) {
  int seg = blockIdx.y;
  const float* W; int N, K; size_t off;
  switch (seg) {
    case 0: W = Wg0; N = 512; K = 256; off = 0;      break;
    case 1: W = Wc0; N = 256; K = 256; off = 131072; break;
    case 2: W = Wg1; N = 512; K = 256; off = 196608; break;
    case 3: W = Wc1; N = 256; K = 256; off = 327680; break;
    case 4: W = Wq;  N = 64;  K = 256; off = 393216; break;
    case 5: W = Wk;  N = 64;  K = 256; off = 409600; break;
    case 6: W = Wv;  N = 64;  K = 256; off = 425984; break;
    default: W = Wo; N = 256; K = 64;  off = 442368; break;
  }
  int total = N * K;
  for (int i = blockIdx.x * 256 + threadIdx.x; i < total; i += 128 * 256) {
    int n = i / K, k = i - n * K;
    Wt[off + (size_t)n * K + k] = __float2bfloat16(W[(size_t)k * N + n]);
  }
}

// ---------------- input projection + LN0: wave per token, 4 tok/block -------
__global__ __launch_bounds__(256) void inproj_ln(
    const float* __restrict__ xc, const float* __restrict__ Wi,
    const float* __restrict__ bi, const float* __restrict__ sc_,
    const float* __restrict__ bb, float* __restrict__ X) {
  int tid = threadIdx.x;
  int tok = blockIdx.x * 4 + (tid >> 6);
  int lane = tid & 63;
  int c0 = lane * 4;
  const float* xr = xc + (size_t)tok * FC;
  float xl[FC];
  #pragma unroll
  for (int i = 0; i < FC; ++i) xl[i] = xr[i];
  float a0 = bi[c0], a1 = bi[c0 + 1], a2 = bi[c0 + 2], a3 = bi[c0 + 3];
  #pragma unroll
  for (int i = 0; i < FC; ++i) {
    const float* wr = Wi + (size_t)i * D_ + c0;
    a0 += xl[i] * wr[0]; a1 += xl[i] * wr[1];
    a2 += xl[i] * wr[2]; a3 += xl[i] * wr[3];
  }
  float m = wave_sum(a0 + a1 + a2 + a3) * (1.f / D_);
  float d0 = a0 - m, d1 = a1 - m, d2 = a2 - m, d3 = a3 - m;
  float var = wave_sum(d0 * d0 + d1 * d1 + d2 * d2 + d3 * d3) * (1.f / D_);
  float rs = rsqrtf(var + EPS);
  float4 o = {d0 * rs * sc_[c0] + bb[c0], d1 * rs * sc_[c0 + 1] + bb[c0 + 1],
              d2 * rs * sc_[c0 + 2] + bb[c0 + 2], d3 * rs * sc_[c0 + 3] + bb[c0 + 3]};
  *(float4*)&X[(size_t)tok * D_ + c0] = o;
}

// ---------------- LN + residual: wave per token, 4 tok/block ----------------
__global__ __launch_bounds__(256) void ln_token_res(
    const float* __restrict__ in, const float* __restrict__ sc_,
    const float* __restrict__ bb, const float* __restrict__ resid,
    float* __restrict__ out) {
  int tid = threadIdx.x;
  int tok = blockIdx.x * 4 + (tid >> 6);
  int lane = tid & 63;
  int c0 = lane * 4;
  float4 v = *(const float4*)&in[(size_t)tok * D_ + c0];
  float m = wave_sum(v.x + v.y + v.z + v.w) * (1.f / D_);
  float d0 = v.x - m, d1 = v.y - m, d2 = v.z - m, d3 = v.w - m;
  float var = wave_sum(d0 * d0 + d1 * d1 + d2 * d2 + d3 * d3) * (1.f / D_);
  float rs = rsqrtf(var + EPS);
  float4 r = *(const float4*)&resid[(size_t)tok * D_ + c0];
  float4 o = {d0 * rs * sc_[c0] + bb[c0] + r.x,
              d1 * rs * sc_[c0 + 1] + bb[c0 + 1] + r.y,
              d2 * rs * sc_[c0 + 2] + bb[c0 + 2] + r.z,
              d3 * rs * sc_[c0 + 3] + bb[c0 + 3] + r.w};
  *(float4*)&out[(size_t)tok * D_ + c0] = o;
}

// ---------------- fused LN2(+res into X) then LN_attn -> O (bf16) -----------
// wave per token, 4 tok/block.
__global__ __launch_bounds__(256) void ln_ln(
    const float* __restrict__ Y, const float* __restrict__ s2,
    const float* __restrict__ b2, float* __restrict__ X,
    const float* __restrict__ sa, const float* __restrict__ ba,
    __hip_bfloat16* __restrict__ O) {
  int tid = threadIdx.x;
  int tok = blockIdx.x * 4 + (tid >> 6);
  int lane = tid & 63;
  int c0 = lane * 4;
  float4 v = *(const float4*)&Y[(size_t)tok * D_ + c0];
  float m = wave_sum(v.x + v.y + v.z + v.w) * (1.f / D_);
  float d0 = v.x - m, d1 = v.y - m, d2 = v.z - m, d3 = v.w - m;
  float var = wave_sum(d0 * d0 + d1 * d1 + d2 * d2 + d3 * d3) * (1.f / D_);
  float rs = rsqrtf(var + EPS);
  float4 xv = *(const float4*)&X[(size_t)tok * D_ + c0];
  float r0 = d0 * rs * s2[c0] + b2[c0] + xv.x;
  float r1 = d1 * rs * s2[c0 + 1] + b2[c0 + 1] + xv.y;
  float r2 = d2 * rs * s2[c0 + 2] + b2[c0 + 2] + xv.z;
  float r3 = d3 * rs * s2[c0 + 3] + b2[c0 + 3] + xv.w;
  float4 xo = {r0, r1, r2, r3};
  *(float4*)&X[(size_t)tok * D_ + c0] = xo;
  float m2 = wave_sum(r0 + r1 + r2 + r3) * (1.f / D_);
  float e0 = r0 - m2, e1 = r1 - m2, e2 = r2 - m2, e3 = r3 - m2;
  float var2 = wave_sum(e0 * e0 + e1 * e1 + e2 * e2 + e3 * e3) * (1.f / D_);
  float rs2 = rsqrtf(var2 + EPS);
  bf16x4 ob;
  ob[0] = f2bf(e0 * rs2 * sa[c0] + ba[c0]);
  ob[1] = f2bf(e1 * rs2 * sa[c0 + 1] + ba[c0 + 1]);
  ob[2] = f2bf(e2 * rs2 * sa[c0 + 2] + ba[c0 + 2]);
  ob[3] = f2bf(e3 * rs2 * sa[c0 + 3] + ba[c0 + 3]);
  *(bf16x4*)&O[(size_t)tok * D_ + c0] = ob;
}

// ---------------- bf16 MFMA GEMM body: BK=64, reg dbuf, K templated ---------
// A [M,K] row-major (fp32 or bf16); Wt bf16 [N,K] row-major (pre-transposed).
// BM=128, 256 thr. Loads for tile kk+64 issued during tile kk's MFMA;
// lgkmcnt-only barriers keep them in flight. OBF=1 -> bf16 out. LDS stride 72.
template <int BN, int KK, typename AT, int OBF>
__device__ __forceinline__ void gemm_body(
    const AT* __restrict__ A, const __hip_bfloat16* __restrict__ Wt,
    const float* __restrict__ bias, const float* __restrict__ resid,
    void* __restrict__ OUTv, int N, int bn0, int act, int res,
    short* As, short* Bs) {
  constexpr int BT = BN / 32;           // B bf16x8 tasks per thread
  constexpr int NT16 = BN / 16;         // n-tiles per wave
  int tid = threadIdx.x;
  int wave = tid >> 6, lane = tid & 63;
  int quad = lane >> 4, m16 = lane & 15;
  int row0 = blockIdx.x * 128;
  const AT* Ag = A + (size_t)row0 * KK;
  const __hip_bfloat16* Wg = Wt + (size_t)bn0 * KK;

  f32x4 acc[2][NT16];
  #pragma unroll
  for (int mt = 0; mt < 2; ++mt)
    #pragma unroll
    for (int nt = 0; nt < NT16; ++nt) acc[mt][nt] = (f32x4){0.f, 0.f, 0.f, 0.f};

  float aRf[4][8];                      // fp32 A staging regs
  bf16x8 aRb[4];                        // bf16 A staging regs
  bf16x8 bRb[BT];                       // bf16 B staging regs

  auto loadA = [&](int kk) {
    #pragma unroll
    for (int i = 0; i < 4; ++i) {
      int idx = tid + i * 256;
      int r = idx >> 3, oct = idx & 7;
      if constexpr (sizeof(AT) == 4) {
        const float* p = (const float*)Ag + (size_t)r * KK + kk + oct * 8;
        float4 x = *(const float4*)p;
        float4 y = *(const float4*)(p + 4);
        aRf[i][0] = x.x; aRf[i][1] = x.y; aRf[i][2] = x.z; aRf[i][3] = x.w;
        aRf[i][4] = y.x; aRf[i][5] = y.y; aRf[i][6] = y.z; aRf[i][7] = y.w;
      } else {
        aRb[i] = *(const bf16x8*)((const __hip_bfloat16*)Ag +
                                  (size_t)r * KK + kk + oct * 8);
      }
    }
  };
  auto loadB = [&](int kk) {
    #pragma unroll
    for (int i = 0; i < BT; ++i) {
      int idx = tid + i * 256;
      int n = idx >> 3, oct = idx & 7;
      bRb[i] = *(const bf16x8*)(Wg + (size_t)n * KK + kk + oct * 8);
    }
  };
  auto storeA = [&]() {
    #pragma unroll
    for (int i = 0; i < 4; ++i) {
      int idx = tid + i * 256;
      int r = idx >> 3, oct = idx & 7;
      if constexpr (sizeof(AT) == 4) {
        bf16x8 v;
        #pragma unroll
        for (int j = 0; j < 8; ++j) v[j] = f2bf(aRf[i][j]);
        *(bf16x8*)&As[r * 72 + oct * 8] = v;
      } else {
        *(bf16x8*)&As[r * 72 + oct * 8] = aRb[i];
      }
    }
  };
  auto storeB = [&]() {
    #pragma unroll
    for (int i = 0; i < BT; ++i) {
      int idx = tid + i * 256;
      int n = idx >> 3, oct = idx & 7;
      *(bf16x8*)&Bs[n * 72 + oct * 8] = bRb[i];
    }
  };

  loadA(0); loadB(0);
  #pragma unroll
  for (int kk = 0; kk < KK; kk += 64) {
    storeA(); storeB();                 // vmcnt wait for staging regs lands here
    __builtin_amdgcn_s_waitcnt(0xC07F); // lgkmcnt(0) only
    __builtin_amdgcn_s_barrier();
    if constexpr (true) {
      if (kk + 64 < KK) { loadA(kk + 64); loadB(kk + 64); }
    }
    #pragma unroll
    for (int kc = 0; kc < 2; ++kc) {
      bf16x8 af0 = *(const bf16x8*)&As[(wave * 32 + m16) * 72 + kc * 32 + quad * 8];
      bf16x8 af1 = *(const bf16x8*)&As[(wave * 32 + 16 + m16) * 72 + kc * 32 + quad * 8];
      #pragma unroll
      for (int nt = 0; nt < NT16; ++nt) {
        bf16x8 bfr = *(const bf16x8*)&Bs[(nt * 16 + m16) * 72 + kc * 32 + quad * 8];
        acc[0][nt] = __builtin_amdgcn_mfma_f32_16x16x32_bf16(af0, bfr, acc[0][nt], 0, 0, 0);
        acc[1][nt] = __builtin_amdgcn_mfma_f32_16x16x32_bf16(af1, bfr, acc[1][nt], 0, 0, 0);
      }
    }
    __builtin_amdgcn_s_waitcnt(0xC07F);
    __builtin_amdgcn_s_barrier();
  }
  // epilogue: C/D layout col=lane&15, row=quad*4+reg
  #pragma unroll
  for (int mt = 0; mt < 2; ++mt) {
    #pragma unroll
    for (int nt = 0; nt < NT16; ++nt) {
      int col = bn0 + nt * 16 + m16;
      float bv = bias[col];
      #pragma unroll
      for (int r = 0; r < 4; ++r) {
        int row = row0 + wave * 32 + mt * 16 + quad * 4 + r;
        float v = acc[mt][nt][r] + bv;
        if (act) v = 1.f / (1.f + __expf(-v));
        if (res) v += resid[(size_t)row * N + col];
        if constexpr (OBF) {
          ((__hip_bfloat16*)OUTv)[(size_t)row * N + col] = __float2bfloat16(v);
        } else {
          ((float*)OUTv)[(size_t)row * N + col] = v;
        }
      }
    }
  }
}

// fused gates+cx. grid (144, 6): y<4 -> G f32 (sigmoid), y>=4 -> C bf16.
__global__ __launch_bounds__(256) void gemm_gru(
    const float* __restrict__ A, const __hip_bfloat16* __restrict__ WtG,
    const float* __restrict__ bg, const __hip_bfloat16* __restrict__ WtC,
    const float* __restrict__ bc, float* __restrict__ G,
    __hip_bfloat16* __restrict__ Cc) {
  __shared__ short As[128 * 72];
  __shared__ short Bs[128 * 72];
  if (blockIdx.y < 4) {
    gemm_body<128, 256, float, 0>(A, WtG, bg, nullptr, (void*)G, 512,
                                  blockIdx.y * 128, 1, 0, As, Bs);
  } else {
    gemm_body<128, 256, float, 1>(A, WtC, bc, nullptr, (void*)Cc, 256,
                                  (blockIdx.y - 4) * 128, 0, 0, As, Bs);
  }
}

// fused Q/K/V from bf16 A. grid (144, 3).
__global__ __launch_bounds__(256) void gemm_qkv(
    const __hip_bfloat16* __restrict__ A, const __hip_bfloat16* __restrict__ Wtq,
    const float* __restrict__ bq, const __hip_bfloat16* __restrict__ Wtk,
    const float* __restrict__ bk, const __hip_bfloat16* __restrict__ Wtv,
    const float* __restrict__ bv, float* __restrict__ Q,
    float* __restrict__ Kb, float* __restrict__ V) {
  __shared__ short As[128 * 72];
  __shared__ short Bs[64 * 72];
  int y = blockIdx.y;
  const __hip_bfloat16* W = (y == 0) ? Wtq : (y == 1) ? Wtk : Wtv;
  const float* bi = (y == 0) ? bq : (y == 1) ? bk : bv;
  float* O = (y == 0) ? Q : (y == 1) ? Kb : V;
  gemm_body<64, 256, __hip_bfloat16, 0>(A, W, bi, nullptr, O, 64, 0, 0, 0, As, Bs);
}

// attention out-proj (bf16 A) with f32 residual. grid (144, 2). K=64.
__global__ __launch_bounds__(256) void gemm_proj(
    const __hip_bfloat16* __restrict__ A, const __hip_bfloat16* __restrict__ Wto,
    const float* __restrict__ bi, const float* __restrict__ resid,
    float* __restrict__ O) {
  __shared__ short As[128 * 72];
  __shared__ short Bs[128 * 72];
  gemm_body<128, 64, __hip_bfloat16, 0>(A, Wto, bi, resid, O, 256,
                                        blockIdx.y * 128, 0, 1, As, Bs);
}

// ---------------- GRU sequential scan (R7/R10 best-known): G f32, C bf16 ----
__global__ __launch_bounds__(512, 2) void gru_scan(
    const float* __restrict__ G, const __hip_bfloat16* __restrict__ C,
    const float* __restrict__ Wch, const float* __restrict__ bch,
    float* __restrict__ Y) {
  __shared__ short vstage[2][256];
  int tid = threadIdx.x;
  int b = blockIdx.x;
  int wave = tid >> 6, lane = tid & 63;
  int quad = lane >> 4, m16 = lane & 15;
  int col0 = 32 * wave + m16;           // tile 2w
  int col1 = col0 + 16;                 // tile 2w+1

  // one-time Wch fragment preload: B-frag[k=32c+quad*8+j][n=col]
  bf16x8 wfrag[2][8];
  #pragma unroll
  for (int tt = 0; tt < 2; ++tt) {
    int n = (tt == 0) ? col0 : col1;
    #pragma unroll
    for (int c = 0; c < 8; ++c) {
      const float* wp = Wch + (size_t)(32 * c + quad * 8) * D_ + n;
      bf16x8 w;
      #pragma unroll
      for (int j = 0; j < 8; ++j) w[j] = f2bf(wp[(size_t)j * D_]);
      wfrag[tt][c] = w;
    }
  }

  const float* Gp = G + (size_t)b * S_ * 512;
  const __hip_bfloat16* Cp = C + (size_t)b * S_ * 256;
  float* Yp = Y + (size_t)b * S_ * 256;

  float bch0 = bch[col0], bch1 = bch[col1];
  float h0 = 0.f, h1 = 0.f;

  float cu0[4], cu1[4], cc0[4], cc1[4], cr0[4], cr1[4];
  #pragma unroll
  for (int i = 0; i < 4; ++i) {
    cu0[i] = Gp[(size_t)i * 512 + 256 + col0];
    cu1[i] = Gp[(size_t)i * 512 + 256 + col1];
    cc0[i] = b2f(Cp[(size_t)i * 256 + col0]);
    cc1[i] = b2f(Cp[(size_t)i * 256 + col1]);
    cr0[i] = Gp[(size_t)(i + 1) * 512 + col0];
    cr1[i] = Gp[(size_t)(i + 1) * 512 + col1];
  }

  if (tid < 256) vstage[0][tid] = 0;    // v_0 = r_0 * h_{-1} = 0
  __syncthreads();

  constexpr int NGRP = S_ / 4;          // 72
  for (int g = 0; g < NGRP; ++g) {
    int gn = (g + 1 < NGRP) ? g + 1 : NGRP - 1;
    const float* Gn = Gp + (size_t)gn * 4 * 512;
    const __hip_bfloat16* Cn = Cp + (size_t)gn * 4 * 256;
    float nu0[4], nu1[4], nc0[4], nc1[4], nr0[4], nr1[4];
    #pragma unroll
    for (int i = 0; i < 4; ++i) {
      nu0[i] = Gn[(size_t)i * 512 + 256 + col0];
      nu1[i] = Gn[(size_t)i * 512 + 256 + col1];
      nc0[i] = b2f(Cn[(size_t)i * 256 + col0]);
      nc1[i] = b2f(Cn[(size_t)i * 256 + col1]);
      int ri = (gn * 4 + i + 1 < S_) ? i + 1 : i;
      nr0[i] = Gn[(size_t)ri * 512 + col0];
      nr1[i] = Gn[(size_t)ri * 512 + col1];
    }
    #pragma unroll
    for (int i = 0; i < 4; ++i) {
      int t = g * 4 + i;
      int buf = t & 1;
      f32x4 A0[4], A1[4];
      #pragma unroll
      for (int j = 0; j < 4; ++j) {
        A0[j] = (f32x4){0.f, 0.f, 0.f, 0.f};
        A1[j] = (f32x4){0.f, 0.f, 0.f, 0.f};
      }
      #pragma unroll
      for (int p = 0; p < 2; ++p) {
        #pragma unroll
        for (int j = 0; j < 4; ++j) {
          int c = p * 4 + j;
          bf16x8 af = *(const bf16x8*)&vstage[buf][(c * 4 + quad) * 8];
          A0[j] = __builtin_amdgcn_mfma_f32_16x16x32_bf16(af, wfrag[0][c], A0[j], 0, 0, 0);
          A1[j] = __builtin_amdgcn_mfma_f32_16x16x32_bf16(af, wfrag[1][c], A1[j], 0, 0, 0);
        }
      }
      float s0 = cc0[i] + bch0 + ((A0[0][0] + A0[1][0]) + (A0[2][0] + A0[3][0]));
      float s1 = cc1[i] + bch1 + ((A1[0][0] + A1[1][0]) + (A1[2][0] + A1[3][0]));
      float e0 = __expf(2.f * s0), e1 = __expf(2.f * s1);
      float cand0 = 1.f - 2.f / (e0 + 1.f);
      float cand1 = 1.f - 2.f / (e1 + 1.f);
      h0 = cu0[i] * h0 + (1.f - cu0[i]) * cand0;
      h1 = cu1[i] * h1 + (1.f - cu1[i]) * cand1;
      short v0 = f2bf(cr0[i] * h0), v1 = f2bf(cr1[i] * h1);
      if (quad == 0) {
        Yp[(size_t)t * 256 + col0] = h0;
        Yp[(size_t)t * 256 + col1] = h1;
        vstage[buf ^ 1][col0] = v0;
        vstage[buf ^ 1][col1] = v1;
      }
      __builtin_amdgcn_s_waitcnt(0xC07F);  // lgkmcnt(0) only
      __builtin_amdgcn_s_barrier();
    }
    #pragma unroll
    for (int i = 0; i < 4; ++i) {
      cu0[i] = nu0[i]; cu1[i] = nu1[i];
      cc0[i] = nc0[i]; cc1[i] = nc1[i];
      cr0[i] = nr0[i]; cr1[i] = nr1[i];
    }
  }
}

// ---------------- flash attention: block=(b,head), 320 thr, K/V in LDS -------
// AO written as bf16.
__global__ __launch_bounds__(320) void attn(
    const float* __restrict__ Q, const float* __restrict__ Kv,
    const float* __restrict__ V, __hip_bfloat16* __restrict__ AO) {
  __shared__ float Kl[S_ * HD];
  __shared__ float Vl[S_ * HD];
  int b = blockIdx.x, hh = blockIdx.y;
  int tid = threadIdx.x;
  int hoff = hh * HD;
  for (int idx = tid; idx < S_ * HD; idx += 320) {
    int row = idx >> 4, d = idx & 15;
    Kl[idx] = Kv[((size_t)(b * S_ + row)) * QKVN + hoff + d];
    Vl[idx] = V[((size_t)(b * S_ + row)) * QKVN + hoff + d];
  }
  __syncthreads();
  if (tid >= S_) return;
  const float* qp = Q + ((size_t)(b * S_ + tid)) * QKVN + hoff;
  float4 q0 = *(const float4*)(qp + 0);
  float4 q1 = *(const float4*)(qp + 4);
  float4 q2 = *(const float4*)(qp + 8);
  float4 q3 = *(const float4*)(qp + 12);
  float m = -1e30f, l = 0.f;
  float4 o0 = {0, 0, 0, 0}, o1 = {0, 0, 0, 0}, o2 = {0, 0, 0, 0},
         o3 = {0, 0, 0, 0};
  for (int k = 0; k < S_; ++k) {
    const float4* kp = (const float4*)&Kl[k * HD];
    float4 k0 = kp[0], k1 = kp[1], k2 = kp[2], k3 = kp[3];
    float s = q0.x * k0.x + q0.y * k0.y + q0.z * k0.z + q0.w * k0.w +
              q1.x * k1.x + q1.y * k1.y + q1.z * k1.z + q1.w * k1.w +
              q2.x * k2.x + q2.y * k2.y + q2.z * k2.z + q2.w * k2.w +
              q3.x * k3.x + q3.y * k3.y + q3.z * k3.z + q3.w * k3.w;
    s *= 0.25f;                          // 1/sqrt(16)
    float mn = fmaxf(m, s);
    float corr = __expf(m - mn);
    float p = __expf(s - mn);
    l = l * corr + p;
    const float4* vp = (const float4*)&Vl[k * HD];
    float4 v0 = vp[0], v1 = vp[1], v2 = vp[2], v3 = vp[3];
    o0.x = o0.x * corr + p * v0.x; o0.y = o0.y * corr + p * v0.y;
    o0.z = o0.z * corr + p * v0.z; o0.w = o0.w * corr + p * v0.w;
    o1.x = o1.x * corr + p * v1.x; o1.y = o1.y * corr + p * v1.y;
    o1.z = o1.z * corr + p * v1.z; o1.w = o1.w * corr + p * v1.w;
    o2.x = o2.x * corr + p * v2.x; o2.y = o2.y * corr + p * v2.y;
    o2.z = o2.z * corr + p * v2.z; o2.w = o2.w * corr + p * v2.w;
    o3.x = o3.x * corr + p * v3.x; o3.y = o3.y * corr + p * v3.y;
    o3.z = o3.z * corr + p * v3.z; o3.w = o3.w * corr + p * v3.w;
    m = mn;
  }
  float inv = 1.f / l;
  __hip_bfloat16* op = AO + ((size_t)(b * S_ + tid)) * QKVN + hoff;
  bf16x8 w0, w1;
  w0[0] = f2bf(o0.x * inv); w0[1] = f2bf(o0.y * inv);
  w0[2] = f2bf(o0.z * inv); w0[3] = f2bf(o0.w * inv);
  w0[4] = f2bf(o1.x * inv); w0[5] = f2bf(o1.y * inv);
  w0[6] = f2bf(o1.z * inv); w0[7] = f2bf(o1.w * inv);
  w1[0] = f2bf(o2.x * inv); w1[1] = f2bf(o2.y * inv);
  w1[2] = f2bf(o2.z * inv); w1[3] = f2bf(o2.w * inv);
  w1[4] = f2bf(o3.x * inv); w1[5] = f2bf(o3.y * inv);
  w1[6] = f2bf(o3.z * inv); w1[7] = f2bf(o3.w * inv);
  *(bf16x8*)op = w0;
  *(bf16x8*)(op + 8) = w1;
}

// ---------------- head: pool + concat + d1(LN) + d2(LN) + out ----------------
__global__ __launch_bounds__(256) void head(
    const float* __restrict__ X, const float* __restrict__ xo,
    const float* __restrict__ Wd1, const float* __restrict__ bd1,
    const float* __restrict__ s1, const float* __restrict__ b1,
    const float* __restrict__ Wd2, const float* __restrict__ bd2,
    const float* __restrict__ s2, const float* __restrict__ b2,
    const float* __restrict__ Wout, const float* __restrict__ bout,
    float* __restrict__ out) {
  __shared__ float c[D_ + FO];
  __shared__ float h1[128];
  __shared__ float sc[8];
  int b = blockIdx.x, tid = threadIdx.x;
  {
    float acc = 0.f;
    const float* xp = X + (size_t)b * S_ * D_ + tid;
    #pragma unroll 4
    for (int t = 0; t < S_; ++t) acc += xp[(size_t)t * D_];
    c[tid] = acc * (1.f / S_);
  }
  if (tid < FO) c[D_ + tid] = xo[b * FO + tid];
  __syncthreads();
  // dense1 (128 outputs) + relu + LN
  float v = 0.f;
  if (tid < 128) {
    v = bd1[tid];
    for (int k = 0; k < D_ + FO; ++k) v += c[k] * Wd1[k * 128 + tid];
    v = fmaxf(v, 0.f);
  }
  float m = blk_sum(tid < 128 ? v : 0.f, sc) * (1.f / 128.f);
  float d = v - m;
  float var = blk_sum(tid < 128 ? d * d : 0.f, sc) * (1.f / 128.f);
  if (tid < 128) h1[tid] = d * rsqrtf(var + EPS) * s1[tid] + b1[tid];
  __syncthreads();
  // dense2 (64 outputs) + relu + LN
  float v2 = 0.f;
  if (tid < 64) {
    v2 = bd2[tid];
    for (int k = 0; k < 128; ++k) v2 += h1[k] * Wd2[k * 64 + tid];
    v2 = fmaxf(v2, 0.f);
  }
  float m2 = blk_sum(tid < 64 ? v2 : 0.f, sc) * (1.f / 64.f);
  float d2v = v2 - m2;
  float var2 = blk_sum(tid < 64 ? d2v * d2v : 0.f, sc) * (1.f / 64.f);
  float hv = (tid < 64) ? (d2v * rsqrtf(var2 + EPS) * s2[tid] + b2[tid]) : 0.f;
  float p = (tid < 64) ? hv * Wout[tid] : 0.f;
  float tot = blk_sum(p, sc);
  if (tid == 0) out[b] = tot + bout[0];
}

extern "C" void kernel_launch(void* const* d_in, const int* in_sizes, int n_in,
                              void* d_out, int out_size, void* d_ws,
                              size_t ws_size, hipStream_t stream) {
  const float* x_cgm = (const float*)d_in[0];
  const float* x_other = (const float*)d_in[1];
  const float* W_in = (const float*)d_in[2];
  const float* b_in = (const float*)d_in[3];
  const float* ln0_s = (const float*)d_in[4];
  const float* ln0_b = (const float*)d_in[5];
  const float* g0_Wg = (const float*)d_in[6];
  const float* g0_bg = (const float*)d_in[7];
  const float* g0_Wcx = (const float*)d_in[8];
  const float* g0_bcx = (const float*)d_in[9];
  const float* g0_Wch = (const float*)d_in[10];
  const float* g0_bch = (const float*)d_in[11];
  const float* g1_Wg = (const float*)d_in[12];
  const float* g1_bg = (const float*)d_in[13];
  const float* g1_Wcx = (const float*)d_in[14];
  const float* g1_bcx = (const float*)d_in[15];
  const float* g1_Wch = (const float*)d_in[16];
  const float* g1_bch = (const float*)d_in[17];
  const float* ln1_s = (const float*)d_in[18];
  const float* ln1_b = (const float*)d_in[19];
  const float* ln2_s = (const float*)d_in[20];
  const float* ln2_b = (const float*)d_in[21];
  const float* aln_s = (const float*)d_in[22];
  const float* aln_b = (const float*)d_in[23];
  const float* Wq = (const float*)d_in[24];
  const float* Wk = (const float*)d_in[25];
  const float* Wv = (const float*)d_in[26];
  const float* bq = (const float*)d_in[27];
  const float* bk = (const float*)d_in[28];
  const float* bv = (const float*)d_in[29];
  const float* Wo = (const float*)d_in[30];
  const float* bo = (const float*)d_in[31];
  const float* Wd1 = (const float*)d_in[32];
  const float* bd1 = (const float*)d_in[33];
  const float* lnd1_s = (const float*)d_in[34];
  const float* lnd1_b = (const float*)d_in[35];
  const float* Wd2 = (const float*)d_in[36];
  const float* bd2 = (const float*)d_in[37];
  const float* lnd2_s = (const float*)d_in[38];
  const float* lnd2_b = (const float*)d_in[39];
  const float* Wout = (const float*)d_in[40];
  const float* bout = (const float*)d_in[41];
  (void)in_sizes; (void)n_in; (void)out_size; (void)ws_size;

  float* ws = (float*)d_ws;
  float* X = ws;                                       // f32 [TOK,256]
  float* Yb = ws + NX;                                 // f32 [TOK,256]
  float* Gb = ws + 2 * NX;                             // f32 [TOK,512]
  __hip_bfloat16* Cb = (__hip_bfloat16*)(ws + 2 * NX + NG); // bf16 [TOK,256]
  __hip_bfloat16* Wt = (__hip_bfloat16*)(ws + 2 * NX + NG + NX / 2);
  // attention-phase reuse:
  float* Qb = Gb;                                      // f32 [TOK,64]
  float* Kbuf = Qb + TOK * QKVN;
  float* Vbuf = Qb + 2 * TOK * QKVN;
  __hip_bfloat16* Obuf = Cb;                           // bf16 ln-attn out
  __hip_bfloat16* AO = (__hip_bfloat16*)Yb;            // bf16 attn out

  // Wt segment offsets (shorts)
  __hip_bfloat16* Wt_g0 = Wt + 0;
  __hip_bfloat16* Wt_c0 = Wt + 131072;
  __hip_bfloat16* Wt_g1 = Wt + 196608;
  __hip_bfloat16* Wt_c1 = Wt + 327680;
  __hip_bfloat16* Wt_q  = Wt + 393216;
  __hip_bfloat16* Wt_k  = Wt + 409600;
  __hip_bfloat16* Wt_v  = Wt + 425984;
  __hip_bfloat16* Wt_o  = Wt + 442368;

  const int MB = TOK / 128;     // 144
  const int LB = TOK / 4;       // 4608 (wave-per-token LN blocks)

  prep_w<<<dim3(128, 8), 256, 0, stream>>>(g0_Wg, g0_Wcx, g1_Wg, g1_Wcx,
                                           Wq, Wk, Wv, Wo, Wt);
  inproj_ln<<<LB, 256, 0, stream>>>(x_cgm, W_in, b_in, ln0_s, ln0_b, X);

  // GRU block 0
  gemm_gru<<<dim3(MB, 6), 256, 0, stream>>>(X, Wt_g0, g0_bg, Wt_c0, g0_bcx, Gb, Cb);
  gru_scan<<<B_, 512, 0, stream>>>(Gb, Cb, g0_Wch, g0_bch, Yb);
  ln_token_res<<<LB, 256, 0, stream>>>(Yb, ln1_s, ln1_b, X, X);

  // GRU block 1
  gemm_gru<<<dim3(MB, 6), 256, 0, stream>>>(X, Wt_g1, g1_bg, Wt_c1, g1_bcx, Gb, Cb);
  gru_scan<<<B_, 512, 0, stream>>>(Gb, Cb, g1_Wch, g1_bch, Yb);

  // fused LN2(+res) and attention-LN -> Obuf (bf16; C dead)
  ln_ln<<<LB, 256, 0, stream>>>(Yb, ln2_s, ln2_b, X, aln_s, aln_b, Obuf);

  // attention
  gemm_qkv<<<dim3(MB, 3), 256, 0, stream>>>(Obuf, Wt_q, bq, Wt_k, bk, Wt_v, bv,
                                            Qb, Kbuf, Vbuf);
  attn<<<dim3(B_, 4), 320, 0, stream>>>(Qb, Kbuf, Vbuf, AO);
  gemm_proj<<<dim3(MB, 2), 256, 0, stream>>>(AO, Wt_o, bo, X, X);

  // head
  head<<<B_, 256, 0, stream>>>(X, x_other, Wd1, bd1, lnd1_s, lnd1_b,
                               Wd2, bd2, lnd2_s, lnd2_b, Wout, bout,
                               (float*)d_out);
}

// Round 15
// 664.033 us; speedup vs baseline: 3.0095x; 1.0135x over previous
//
#include <hip/hip_runtime.h>
#include <hip/hip_bf16.h>
#include <math.h>

// GRUModel: B=64,S=288,Fc=16,Fo=32,D=256,QKV=64,HEADS=4,hd=16
// Round 15: LN producers dual-write X (f32, residual chain) + Xbf (bf16);
// gemm_gru consumes bf16 A -> zero f32->bf16 cvts and half the A bytes in
// staging (same rounding, moved upstream: absmax must stay 0.0098).
// Scan frozen at R10 shape. Rest identical to R14.
// ws (floats): X[NX] | Yb[NX] | G f32[NG] | C bf16[NX/2] | Wt[229K] | Xbf[NX/2]

#define EPS 1e-5f
constexpr int B_ = 64, S_ = 288, FC = 16, FO = 32, D_ = 256, QKVN = 64, HD = 16;
constexpr int TOK = B_ * S_;            // 18432
constexpr int NX = TOK * D_;            // 4718592
constexpr int NG = TOK * 512;           // 9437184

typedef short bf16x8 __attribute__((ext_vector_type(8)));
typedef short bf16x4 __attribute__((ext_vector_type(4)));
typedef float f32x4 __attribute__((ext_vector_type(4)));

__device__ __forceinline__ short f2bf(float f) {
  __hip_bfloat16 h = __float2bfloat16(f);
  return __builtin_bit_cast(short, h);
}
__device__ __forceinline__ float b2f(__hip_bfloat16 h) {
  return __bfloat162float(h);
}

// wave-wide sum, result broadcast to all 64 lanes.
__device__ __forceinline__ float wave_sum(float v) {
  #pragma unroll
  for (int o = 32; o > 0; o >>= 1) v += __shfl_down(v, o, 64);
  return __shfl(v, 0, 64);
}

// block-wide sum; blockDim multiple of 64, <=512. sc: >= blockDim/64 floats.
__device__ __forceinline__ float blk_sum(float v, float* sc) {
  #pragma unroll
  for (int o = 32; o > 0; o >>= 1) v += __shfl_down(v, o, 64);
  int tid = threadIdx.x;
  int wid = tid >> 6, nw = blockDim.x >> 6;
  __syncthreads();                      // protect sc from previous use
  if ((tid & 63) == 0) sc[wid] = v;
  __syncthreads();
  float s = 0.f;
  for (int w = 0; w < nw; ++w) s += sc[w];
  return s;
}

// ---------------- weight prep: fp32 [K,N] -> bf16 [N,K] ---------------------
__global__ __launch_bounds__(256) void prep_w(
    const float* __restrict__ Wg0, const float* __restrict__ Wc0,
    const float* __restrict__ Wg1, const float* __restrict__ Wc1,
    const float* __restrict__ Wq, const float* __restrict__ Wk,
    const float* __restrict__ Wv, const float* __restrict__ Wo,
    __hip_bfloat16* __restrict__ Wt) {
  int seg = blockIdx.y;
  const float* W; int N, K; size_t off;
  switch (seg) {
    case 0: W = Wg0; N = 512; K = 256; off = 0;      break;
    case 1: W = Wc0; N = 256; K = 256; off = 131072; break;
    case 2: W = Wg1; N = 512; K = 256; off = 196608; break;
    case 3: W = Wc1; N = 256; K = 256; off = 327680; break;
    case 4: W = Wq;  N = 64;  K = 256; off = 393216; break;
    case 5: W = Wk;  N = 64;  K = 256; off = 409600; break;
    case 6: W = Wv;  N = 64;  K = 256; off = 425984; break;
    default: W = Wo; N = 256; K = 64;  off = 442368; break;
  }
  int total = N * K;
  for (int i = blockIdx.x * 256 + threadIdx.x; i < total; i += 128 * 256) {
    int n = i / K, k = i - n * K;
    Wt[off + (size_t)n * K + k] = __float2bfloat16(W[(size_t)k * N + n]);
  }
}

// ---------------- input projection + LN0: wave per token, 4 tok/block -------
// dual-writes X (f32) and Xbf (bf16).
__global__ __launch_bounds__(256) void inproj_ln(
    const float* __restrict__ xc, const float* __restrict__ Wi,
    const float* __restrict__ bi, const float* __restrict__ sc_,
    const float* __restrict__ bb, float* __restrict__ X,
    __hip_bfloat16* __restrict__ Xbf) {
  int tid = threadIdx.x;
  int tok = blockIdx.x * 4 + (tid >> 6);
  int lane = tid & 63;
  int c0 = lane * 4;
  const float* xr = xc + (size_t)tok * FC;
  float xl[FC];
  #pragma unroll
  for (int i = 0; i < FC; ++i) xl[i] = xr[i];
  float a0 = bi[c0], a1 = bi[c0 + 1], a2 = bi[c0 + 2], a3 = bi[c0 + 3];
  #pragma unroll
  for (int i = 0; i < FC; ++i) {
    const float* wr = Wi + (size_t)i * D_ + c0;
    a0 += xl[i] * wr[0]; a1 += xl[i] * wr[1];
    a2 += xl[i] * wr[2]; a3 += xl[i] * wr[3];
  }
  float m = wave_sum(a0 + a1 + a2 + a3) * (1.f / D_);
  float d0 = a0 - m, d1 = a1 - m, d2 = a2 - m, d3 = a3 - m;
  float var = wave_sum(d0 * d0 + d1 * d1 + d2 * d2 + d3 * d3) * (1.f / D_);
  float rs = rsqrtf(var + EPS);
  float4 o = {d0 * rs * sc_[c0] + bb[c0], d1 * rs * sc_[c0 + 1] + bb[c0 + 1],
              d2 * rs * sc_[c0 + 2] + bb[c0 + 2], d3 * rs * sc_[c0 + 3] + bb[c0 + 3]};
  *(float4*)&X[(size_t)tok * D_ + c0] = o;
  bf16x4 ob = {f2bf(o.x), f2bf(o.y), f2bf(o.z), f2bf(o.w)};
  *(bf16x4*)&Xbf[(size_t)tok * D_ + c0] = ob;
}

// ---------------- LN + residual: wave per token, 4 tok/block ----------------
// dual-writes out (f32) and outbf (bf16).
__global__ __launch_bounds__(256) void ln_token_res(
    const float* __restrict__ in, const float* __restrict__ sc_,
    const float* __restrict__ bb, const float* __restrict__ resid,
    float* __restrict__ out, __hip_bfloat16* __restrict__ outbf) {
  int tid = threadIdx.x;
  int tok = blockIdx.x * 4 + (tid >> 6);
  int lane = tid & 63;
  int c0 = lane * 4;
  float4 v = *(const float4*)&in[(size_t)tok * D_ + c0];
  float m = wave_sum(v.x + v.y + v.z + v.w) * (1.f / D_);
  float d0 = v.x - m, d1 = v.y - m, d2 = v.z - m, d3 = v.w - m;
  float var = wave_sum(d0 * d0 + d1 * d1 + d2 * d2 + d3 * d3) * (1.f / D_);
  float rs = rsqrtf(var + EPS);
  float4 r = *(const float4*)&resid[(size_t)tok * D_ + c0];
  float4 o = {d0 * rs * sc_[c0] + bb[c0] + r.x,
              d1 * rs * sc_[c0 + 1] + bb[c0 + 1] + r.y,
              d2 * rs * sc_[c0 + 2] + bb[c0 + 2] + r.z,
              d3 * rs * sc_[c0 + 3] + bb[c0 + 3] + r.w};
  *(float4*)&out[(size_t)tok * D_ + c0] = o;
  bf16x4 ob = {f2bf(o.x), f2bf(o.y), f2bf(o.z), f2bf(o.w)};
  *(bf16x4*)&outbf[(size_t)tok * D_ + c0] = ob;
}

// ---------------- fused LN2(+res into X) then LN_attn -> O (bf16) -----------
// wave per token, 4 tok/block.
__global__ __launch_bounds__(256) void ln_ln(
    const float* __restrict__ Y, const float* __restrict__ s2,
    const float* __restrict__ b2, float* __restrict__ X,
    const float* __restrict__ sa, const float* __restrict__ ba,
    __hip_bfloat16* __restrict__ O) {
  int tid = threadIdx.x;
  int tok = blockIdx.x * 4 + (tid >> 6);
  int lane = tid & 63;
  int c0 = lane * 4;
  float4 v = *(const float4*)&Y[(size_t)tok * D_ + c0];
  float m = wave_sum(v.x + v.y + v.z + v.w) * (1.f / D_);
  float d0 = v.x - m, d1 = v.y - m, d2 = v.z - m, d3 = v.w - m;
  float var = wave_sum(d0 * d0 + d1 * d1 + d2 * d2 + d3 * d3) * (1.f / D_);
  float rs = rsqrtf(var + EPS);
  float4 xv = *(const float4*)&X[(size_t)tok * D_ + c0];
  float r0 = d0 * rs * s2[c0] + b2[c0] + xv.x;
  float r1 = d1 * rs * s2[c0 + 1] + b2[c0 + 1] + xv.y;
  float r2 = d2 * rs * s2[c0 + 2] + b2[c0 + 2] + xv.z;
  float r3 = d3 * rs * s2[c0 + 3] + b2[c0 + 3] + xv.w;
  float4 xo = {r0, r1, r2, r3};
  *(float4*)&X[(size_t)tok * D_ + c0] = xo;
  float m2 = wave_sum(r0 + r1 + r2 + r3) * (1.f / D_);
  float e0 = r0 - m2, e1 = r1 - m2, e2 = r2 - m2, e3 = r3 - m2;
  float var2 = wave_sum(e0 * e0 + e1 * e1 + e2 * e2 + e3 * e3) * (1.f / D_);
  float rs2 = rsqrtf(var2 + EPS);
  bf16x4 ob;
  ob[0] = f2bf(e0 * rs2 * sa[c0] + ba[c0]);
  ob[1] = f2bf(e1 * rs2 * sa[c0 + 1] + ba[c0 + 1]);
  ob[2] = f2bf(e2 * rs2 * sa[c0 + 2] + ba[c0 + 2]);
  ob[3] = f2bf(e3 * rs2 * sa[c0 + 3] + ba[c0 + 3]);
  *(bf16x4*)&O[(size_t)tok * D_ + c0] = ob;
}

// ---------------- bf16 MFMA GEMM body: BK=64, reg dbuf, K templated ---------
// A bf16 [M,K] row-major; Wt bf16 [N,K] row-major (pre-transposed).
// BM=128, 256 thr. Loads for tile kk+64 issued during tile kk's MFMA;
// lgkmcnt-only barriers keep them in flight. OBF=1 -> bf16 out. LDS stride 72.
template <int BN, int KK, int OBF>
__device__ __forceinline__ void gemm_body(
    const __hip_bfloat16* __restrict__ A, const __hip_bfloat16* __restrict__ Wt,
    const float* __restrict__ bias, const float* __restrict__ resid,
    void* __restrict__ OUTv, int N, int bn0, int act, int res,
    short* As, short* Bs) {
  constexpr int BT = BN / 32;           // B bf16x8 tasks per thread
  constexpr int NT16 = BN / 16;         // n-tiles per wave
  int tid = threadIdx.x;
  int wave = tid >> 6, lane = tid & 63;
  int quad = lane >> 4, m16 = lane & 15;
  int row0 = blockIdx.x * 128;
  const __hip_bfloat16* Ag = A + (size_t)row0 * KK;
  const __hip_bfloat16* Wg = Wt + (size_t)bn0 * KK;

  f32x4 acc[2][NT16];
  #pragma unroll
  for (int mt = 0; mt < 2; ++mt)
    #pragma unroll
    for (int nt = 0; nt < NT16; ++nt) acc[mt][nt] = (f32x4){0.f, 0.f, 0.f, 0.f};

  bf16x8 aRb[4];                        // bf16 A staging regs
  bf16x8 bRb[BT];                       // bf16 B staging regs

  auto loadA = [&](int kk) {
    #pragma unroll
    for (int i = 0; i < 4; ++i) {
      int idx = tid + i * 256;
      int r = idx >> 3, oct = idx & 7;
      aRb[i] = *(const bf16x8*)(Ag + (size_t)r * KK + kk + oct * 8);
    }
  };
  auto loadB = [&](int kk) {
    #pragma unroll
    for (int i = 0; i < BT; ++i) {
      int idx = tid + i * 256;
      int n = idx >> 3, oct = idx & 7;
      bRb[i] = *(const bf16x8*)(Wg + (size_t)n * KK + kk + oct * 8);
    }
  };
  auto storeA = [&]() {
    #pragma unroll
    for (int i = 0; i < 4; ++i) {
      int idx = tid + i * 256;
      int r = idx >> 3, oct = idx & 7;
      *(bf16x8*)&As[r * 72 + oct * 8] = aRb[i];
    }
  };
  auto storeB = [&]() {
    #pragma unroll
    for (int i = 0; i < BT; ++i) {
      int idx = tid + i * 256;
      int n = idx >> 3, oct = idx & 7;
      *(bf16x8*)&Bs[n * 72 + oct * 8] = bRb[i];
    }
  };

  loadA(0); loadB(0);
  #pragma unroll
  for (int kk = 0; kk < KK; kk += 64) {
    storeA(); storeB();                 // vmcnt wait for staging regs lands here
    __builtin_amdgcn_s_waitcnt(0xC07F); // lgkmcnt(0) only
    __builtin_amdgcn_s_barrier();
    if (kk + 64 < KK) { loadA(kk + 64); loadB(kk + 64); }
    #pragma unroll
    for (int kc = 0; kc < 2; ++kc) {
      bf16x8 af0 = *(const bf16x8*)&As[(wave * 32 + m16) * 72 + kc * 32 + quad * 8];
      bf16x8 af1 = *(const bf16x8*)&As[(wave * 32 + 16 + m16) * 72 + kc * 32 + quad * 8];
      #pragma unroll
      for (int nt = 0; nt < NT16; ++nt) {
        bf16x8 bfr = *(const bf16x8*)&Bs[(nt * 16 + m16) * 72 + kc * 32 + quad * 8];
        acc[0][nt] = __builtin_amdgcn_mfma_f32_16x16x32_bf16(af0, bfr, acc[0][nt], 0, 0, 0);
        acc[1][nt] = __builtin_amdgcn_mfma_f32_16x16x32_bf16(af1, bfr, acc[1][nt], 0, 0, 0);
      }
    }
    __builtin_amdgcn_s_waitcnt(0xC07F);
    __builtin_amdgcn_s_barrier();
  }
  // epilogue: C/D layout col=lane&15, row=quad*4+reg
  #pragma unroll
  for (int mt = 0; mt < 2; ++mt) {
    #pragma unroll
    for (int nt = 0; nt < NT16; ++nt) {
      int col = bn0 + nt * 16 + m16;
      float bv = bias[col];
      #pragma unroll
      for (int r = 0; r < 4; ++r) {
        int row = row0 + wave * 32 + mt * 16 + quad * 4 + r;
        float v = acc[mt][nt][r] + bv;
        if (act) v = 1.f / (1.f + __expf(-v));
        if (res) v += resid[(size_t)row * N + col];
        if constexpr (OBF) {
          ((__hip_bfloat16*)OUTv)[(size_t)row * N + col] = __float2bfloat16(v);
        } else {
          ((float*)OUTv)[(size_t)row * N + col] = v;
        }
      }
    }
  }
}

// fused gates+cx (bf16 A). grid (144, 6): y<4 -> G f32 (sigmoid), y>=4 -> C bf16.
__global__ __launch_bounds__(256) void gemm_gru(
    const __hip_bfloat16* __restrict__ A, const __hip_bfloat16* __restrict__ WtG,
    const float* __restrict__ bg, const __hip_bfloat16* __restrict__ WtC,
    const float* __restrict__ bc, float* __restrict__ G,
    __hip_bfloat16* __restrict__ Cc) {
  __shared__ short As[128 * 72];
  __shared__ short Bs[128 * 72];
  if (blockIdx.y < 4) {
    gemm_body<128, 256, 0>(A, WtG, bg, nullptr, (void*)G, 512,
                           blockIdx.y * 128, 1, 0, As, Bs);
  } else {
    gemm_body<128, 256, 1>(A, WtC, bc, nullptr, (void*)Cc, 256,
                           (blockIdx.y - 4) * 128, 0, 0, As, Bs);
  }
}

// fused Q/K/V from bf16 A. grid (144, 3).
__global__ __launch_bounds__(256) void gemm_qkv(
    const __hip_bfloat16* __restrict__ A, const __hip_bfloat16* __restrict__ Wtq,
    const float* __restrict__ bq, const __hip_bfloat16* __restrict__ Wtk,
    const float* __restrict__ bk, const __hip_bfloat16* __restrict__ Wtv,
    const float* __restrict__ bv, float* __restrict__ Q,
    float* __restrict__ Kb, float* __restrict__ V) {
  __shared__ short As[128 * 72];
  __shared__ short Bs[64 * 72];
  int y = blockIdx.y;
  const __hip_bfloat16* W = (y == 0) ? Wtq : (y == 1) ? Wtk : Wtv;
  const float* bi = (y == 0) ? bq : (y == 1) ? bk : bv;
  float* O = (y == 0) ? Q : (y == 1) ? Kb : V;
  gemm_body<64, 256, 0>(A, W, bi, nullptr, O, 64, 0, 0, 0, As, Bs);
}

// attention out-proj (bf16 A) with f32 residual. grid (144, 2). K=64.
__global__ __launch_bounds__(256) void gemm_proj(
    const __hip_bfloat16* __restrict__ A, const __hip_bfloat16* __restrict__ Wto,
    const float* __restrict__ bi, const float* __restrict__ resid,
    float* __restrict__ O) {
  __shared__ short As[128 * 72];
  __shared__ short Bs[128 * 72];
  gemm_body<128, 64, 0>(A, Wto, bi, resid, O, 256, blockIdx.y * 128, 0, 1,
                        As, Bs);
}

// ---------------- GRU sequential scan (R7/R10 best-known): G f32, C bf16 ----
__global__ __launch_bounds__(512, 2) void gru_scan(
    const float* __restrict__ G, const __hip_bfloat16* __restrict__ C,
    const float* __restrict__ Wch, const float* __restrict__ bch,
    float* __restrict__ Y) {
  __shared__ short vstage[2][256];
  int tid = threadIdx.x;
  int b = blockIdx.x;
  int wave = tid >> 6, lane = tid & 63;
  int quad = lane >> 4, m16 = lane & 15;
  int col0 = 32 * wave + m16;           // tile 2w
  int col1 = col0 + 16;                 // tile 2w+1

  // one-time Wch fragment preload: B-frag[k=32c+quad*8+j][n=col]
  bf16x8 wfrag[2][8];
  #pragma unroll
  for (int tt = 0; tt < 2; ++tt) {
    int n = (tt == 0) ? col0 : col1;
    #pragma unroll
    for (int c = 0; c < 8; ++c) {
      const float* wp = Wch + (size_t)(32 * c + quad * 8) * D_ + n;
      bf16x8 w;
      #pragma unroll
      for (int j = 0; j < 8; ++j) w[j] = f2bf(wp[(size_t)j * D_]);
      wfrag[tt][c] = w;
    }
  }

  const float* Gp = G + (size_t)b * S_ * 512;
  const __hip_bfloat16* Cp = C + (size_t)b * S_ * 256;
  float* Yp = Y + (size_t)b * S_ * 256;

  float bch0 = bch[col0], bch1 = bch[col1];
  float h0 = 0.f, h1 = 0.f;

  float cu0[4], cu1[4], cc0[4], cc1[4], cr0[4], cr1[4];
  #pragma unroll
  for (int i = 0; i < 4; ++i) {
    cu0[i] = Gp[(size_t)i * 512 + 256 + col0];
    cu1[i] = Gp[(size_t)i * 512 + 256 + col1];
    cc0[i] = b2f(Cp[(size_t)i * 256 + col0]);
    cc1[i] = b2f(Cp[(size_t)i * 256 + col1]);
    cr0[i] = Gp[(size_t)(i + 1) * 512 + col0];
    cr1[i] = Gp[(size_t)(i + 1) * 512 + col1];
  }

  if (tid < 256) vstage[0][tid] = 0;    // v_0 = r_0 * h_{-1} = 0
  __syncthreads();

  constexpr int NGRP = S_ / 4;          // 72
  for (int g = 0; g < NGRP; ++g) {
    int gn = (g + 1 < NGRP) ? g + 1 : NGRP - 1;
    const float* Gn = Gp + (size_t)gn * 4 * 512;
    const __hip_bfloat16* Cn = Cp + (size_t)gn * 4 * 256;
    float nu0[4], nu1[4], nc0[4], nc1[4], nr0[4], nr1[4];
    #pragma unroll
    for (int i = 0; i < 4; ++i) {
      nu0[i] = Gn[(size_t)i * 512 + 256 + col0];
      nu1[i] = Gn[(size_t)i * 512 + 256 + col1];
      nc0[i] = b2f(Cn[(size_t)i * 256 + col0]);
      nc1[i] = b2f(Cn[(size_t)i * 256 + col1]);
      int ri = (gn * 4 + i + 1 < S_) ? i + 1 : i;
      nr0[i] = Gn[(size_t)ri * 512 + col0];
      nr1[i] = Gn[(size_t)ri * 512 + col1];
    }
    #pragma unroll
    for (int i = 0; i < 4; ++i) {
      int t = g * 4 + i;
      int buf = t & 1;
      f32x4 A0[4], A1[4];
      #pragma unroll
      for (int j = 0; j < 4; ++j) {
        A0[j] = (f32x4){0.f, 0.f, 0.f, 0.f};
        A1[j] = (f32x4){0.f, 0.f, 0.f, 0.f};
      }
      #pragma unroll
      for (int p = 0; p < 2; ++p) {
        #pragma unroll
        for (int j = 0; j < 4; ++j) {
          int c = p * 4 + j;
          bf16x8 af = *(const bf16x8*)&vstage[buf][(c * 4 + quad) * 8];
          A0[j] = __builtin_amdgcn_mfma_f32_16x16x32_bf16(af, wfrag[0][c], A0[j], 0, 0, 0);
          A1[j] = __builtin_amdgcn_mfma_f32_16x16x32_bf16(af, wfrag[1][c], A1[j], 0, 0, 0);
        }
      }
      float s0 = cc0[i] + bch0 + ((A0[0][0] + A0[1][0]) + (A0[2][0] + A0[3][0]));
      float s1 = cc1[i] + bch1 + ((A1[0][0] + A1[1][0]) + (A1[2][0] + A1[3][0]));
      float e0 = __expf(2.f * s0), e1 = __expf(2.f * s1);
      float cand0 = 1.f - 2.f / (e0 + 1.f);
      float cand1 = 1.f - 2.f / (e1 + 1.f);
      h0 = cu0[i] * h0 + (1.f - cu0[i]) * cand0;
      h1 = cu1[i] * h1 + (1.f - cu1[i]) * cand1;
      short v0 = f2bf(cr0[i] * h0), v1 = f2bf(cr1[i] * h1);
      if (quad == 0) {
        Yp[(size_t)t * 256 + col0] = h0;
        Yp[(size_t)t * 256 + col1] = h1;
        vstage[buf ^ 1][col0] = v0;
        vstage[buf ^ 1][col1] = v1;
      }
      __builtin_amdgcn_s_waitcnt(0xC07F);  // lgkmcnt(0) only
      __builtin_amdgcn_s_barrier();
    }
    #pragma unroll
    for (int i = 0; i < 4; ++i) {
      cu0[i] = nu0[i]; cu1[i] = nu1[i];
      cc0[i] = nc0[i]; cc1[i] = nc1[i];
      cr0[i] = nr0[i]; cr1[i] = nr1[i];
    }
  }
}

// ---------------- flash attention: block=(b,head), 320 thr, K/V in LDS -------
// AO written as bf16.
__global__ __launch_bounds__(320) void attn(
    const float* __restrict__ Q, const float* __restrict__ Kv,
    const float* __restrict__ V, __hip_bfloat16* __restrict__ AO) {
  __shared__ float Kl[S_ * HD];
  __shared__ float Vl[S_ * HD];
  int b = blockIdx.x, hh = blockIdx.y;
  int tid = threadIdx.x;
  int hoff = hh * HD;
  for (int idx = tid; idx < S_ * HD; idx += 320) {
    int row = idx >> 4, d = idx & 15;
    Kl[idx] = Kv[((size_t)(b * S_ + row)) * QKVN + hoff + d];
    Vl[idx] = V[((size_t)(b * S_ + row)) * QKVN + hoff + d];
  }
  __syncthreads();
  if (tid >= S_) return;
  const float* qp = Q + ((size_t)(b * S_ + tid)) * QKVN + hoff;
  float4 q0 = *(const float4*)(qp + 0);
  float4 q1 = *(const float4*)(qp + 4);
  float4 q2 = *(const float4*)(qp + 8);
  float4 q3 = *(const float4*)(qp + 12);
  float m = -1e30f, l = 0.f;
  float4 o0 = {0, 0, 0, 0}, o1 = {0, 0, 0, 0}, o2 = {0, 0, 0, 0},
         o3 = {0, 0, 0, 0};
  for (int k = 0; k < S_; ++k) {
    const float4* kp = (const float4*)&Kl[k * HD];
    float4 k0 = kp[0], k1 = kp[1], k2 = kp[2], k3 = kp[3];
    float s = q0.x * k0.x + q0.y * k0.y + q0.z * k0.z + q0.w * k0.w +
              q1.x * k1.x + q1.y * k1.y + q1.z * k1.z + q1.w * k1.w +
              q2.x * k2.x + q2.y * k2.y + q2.z * k2.z + q2.w * k2.w +
              q3.x * k3.x + q3.y * k3.y + q3.z * k3.z + q3.w * k3.w;
    s *= 0.25f;                          // 1/sqrt(16)
    float mn = fmaxf(m, s);
    float corr = __expf(m - mn);
    float p = __expf(s - mn);
    l = l * corr + p;
    const float4* vp = (const float4*)&Vl[k * HD];
    float4 v0 = vp[0], v1 = vp[1], v2 = vp[2], v3 = vp[3];
    o0.x = o0.x * corr + p * v0.x; o0.y = o0.y * corr + p * v0.y;
    o0.z = o0.z * corr + p * v0.z; o0.w = o0.w * corr + p * v0.w;
    o1.x = o1.x * corr + p * v1.x; o1.y = o1.y * corr + p * v1.y;
    o1.z = o1.z * corr + p * v1.z; o1.w = o1.w * corr + p * v1.w;
    o2.x = o2.x * corr + p * v2.x; o2.y = o2.y * corr + p * v2.y;
    o2.z = o2.z * corr + p * v2.z; o2.w = o2.w * corr + p * v2.w;
    o3.x = o3.x * corr + p * v3.x; o3.y = o3.y * corr + p * v3.y;
    o3.z = o3.z * corr + p * v3.z; o3.w = o3.w * corr + p * v3.w;
    m = mn;
  }
  float inv = 1.f / l;
  __hip_bfloat16* op = AO + ((size_t)(b * S_ + tid)) * QKVN + hoff;
  bf16x8 w0, w1;
  w0[0] = f2bf(o0.x * inv); w0[1] = f2bf(o0.y * inv);
  w0[2] = f2bf(o0.z * inv); w0[3] = f2bf(o0.w * inv);
  w0[4] = f2bf(o1.x * inv); w0[5] = f2bf(o1.y * inv);
  w0[6] = f2bf(o1.z * inv); w0[7] = f2bf(o1.w * inv);
  w1[0] = f2bf(o2.x * inv); w1[1] = f2bf(o2.y * inv);
  w1[2] = f2bf(o2.z * inv); w1[3] = f2bf(o2.w * inv);
  w1[4] = f2bf(o3.x * inv); w1[5] = f2bf(o3.y * inv);
  w1[6] = f2bf(o3.z * inv); w1[7] = f2bf(o3.w * inv);
  *(bf16x8*)op = w0;
  *(bf16x8*)(op + 8) = w1;
}

// ---------------- head: pool + concat + d1(LN) + d2(LN) + out ----------------
__global__ __launch_bounds__(256) void head(
    const float* __restrict__ X, const float* __restrict__ xo,
    const float* __restrict__ Wd1, const float* __restrict__ bd1,
    const float* __restrict__ s1, const float* __restrict__ b1,
    const float* __restrict__ Wd2, const float* __restrict__ bd2,
    const float* __restrict__ s2, const float* __restrict__ b2,
    const float* __restrict__ Wout, const float* __restrict__ bout,
    float* __restrict__ out) {
  __shared__ float c[D_ + FO];
  __shared__ float h1[128];
  __shared__ float sc[8];
  int b = blockIdx.x, tid = threadIdx.x;
  {
    float acc = 0.f;
    const float* xp = X + (size_t)b * S_ * D_ + tid;
    #pragma unroll 4
    for (int t = 0; t < S_; ++t) acc += xp[(size_t)t * D_];
    c[tid] = acc * (1.f / S_);
  }
  if (tid < FO) c[D_ + tid] = xo[b * FO + tid];
  __syncthreads();
  // dense1 (128 outputs) + relu + LN
  float v = 0.f;
  if (tid < 128) {
    v = bd1[tid];
    for (int k = 0; k < D_ + FO; ++k) v += c[k] * Wd1[k * 128 + tid];
    v = fmaxf(v, 0.f);
  }
  float m = blk_sum(tid < 128 ? v : 0.f, sc) * (1.f / 128.f);
  float d = v - m;
  float var = blk_sum(tid < 128 ? d * d : 0.f, sc) * (1.f / 128.f);
  if (tid < 128) h1[tid] = d * rsqrtf(var + EPS) * s1[tid] + b1[tid];
  __syncthreads();
  // dense2 (64 outputs) + relu + LN
  float v2 = 0.f;
  if (tid < 64) {
    v2 = bd2[tid];
    for (int k = 0; k < 128; ++k) v2 += h1[k] * Wd2[k * 64 + tid];
    v2 = fmaxf(v2, 0.f);
  }
  float m2 = blk_sum(tid < 64 ? v2 : 0.f, sc) * (1.f / 64.f);
  float d2v = v2 - m2;
  float var2 = blk_sum(tid < 64 ? d2v * d2v : 0.f, sc) * (1.f / 64.f);
  float hv = (tid < 64) ? (d2v * rsqrtf(var2 + EPS) * s2[tid] + b2[tid]) : 0.f;
  float p = (tid < 64) ? hv * Wout[tid] : 0.f;
  float tot = blk_sum(p, sc);
  if (tid == 0) out[b] = tot + bout[0];
}

extern "C" void kernel_launch(void* const* d_in, const int* in_sizes, int n_in,
                              void* d_out, int out_size, void* d_ws,
                              size_t ws_size, hipStream_t stream) {
  const float* x_cgm = (const float*)d_in[0];
  const float* x_other = (const float*)d_in[1];
  const float* W_in = (const float*)d_in[2];
  const float* b_in = (const float*)d_in[3];
  const float* ln0_s = (const float*)d_in[4];
  const float* ln0_b = (const float*)d_in[5];
  const float* g0_Wg = (const float*)d_in[6];
  const float* g0_bg = (const float*)d_in[7];
  const float* g0_Wcx = (const float*)d_in[8];
  const float* g0_bcx = (const float*)d_in[9];
  const float* g0_Wch = (const float*)d_in[10];
  const float* g0_bch = (const float*)d_in[11];
  const float* g1_Wg = (const float*)d_in[12];
  const float* g1_bg = (const float*)d_in[13];
  const float* g1_Wcx = (const float*)d_in[14];
  const float* g1_bcx = (const float*)d_in[15];
  const float* g1_Wch = (const float*)d_in[16];
  const float* g1_bch = (const float*)d_in[17];
  const float* ln1_s = (const float*)d_in[18];
  const float* ln1_b = (const float*)d_in[19];
  const float* ln2_s = (const float*)d_in[20];
  const float* ln2_b = (const float*)d_in[21];
  const float* aln_s = (const float*)d_in[22];
  const float* aln_b = (const float*)d_in[23];
  const float* Wq = (const float*)d_in[24];
  const float* Wk = (const float*)d_in[25];
  const float* Wv = (const float*)d_in[26];
  const float* bq = (const float*)d_in[27];
  const float* bk = (const float*)d_in[28];
  const float* bv = (const float*)d_in[29];
  const float* Wo = (const float*)d_in[30];
  const float* bo = (const float*)d_in[31];
  const float* Wd1 = (const float*)d_in[32];
  const float* bd1 = (const float*)d_in[33];
  const float* lnd1_s = (const float*)d_in[34];
  const float* lnd1_b = (const float*)d_in[35];
  const float* Wd2 = (const float*)d_in[36];
  const float* bd2 = (const float*)d_in[37];
  const float* lnd2_s = (const float*)d_in[38];
  const float* lnd2_b = (const float*)d_in[39];
  const float* Wout = (const float*)d_in[40];
  const float* bout = (const float*)d_in[41];
  (void)in_sizes; (void)n_in; (void)out_size; (void)ws_size;

  float* ws = (float*)d_ws;
  float* X = ws;                                       // f32 [TOK,256]
  float* Yb = ws + NX;                                 // f32 [TOK,256]
  float* Gb = ws + 2 * NX;                             // f32 [TOK,512]
  __hip_bfloat16* Cb = (__hip_bfloat16*)(ws + 2 * NX + NG); // bf16 [TOK,256]
  __hip_bfloat16* Wt = (__hip_bfloat16*)(ws + 2 * NX + NG + NX / 2);
  __hip_bfloat16* Xbf = (__hip_bfloat16*)(ws + 2 * NX + NG + NX / 2 + 229376);
  // attention-phase reuse:
  float* Qb = Gb;                                      // f32 [TOK,64]
  float* Kbuf = Qb + TOK * QKVN;
  float* Vbuf = Qb + 2 * TOK * QKVN;
  __hip_bfloat16* Obuf = Cb;                           // bf16 ln-attn out
  __hip_bfloat16* AO = (__hip_bfloat16*)Yb;            // bf16 attn out

  // Wt segment offsets (shorts)
  __hip_bfloat16* Wt_g0 = Wt + 0;
  __hip_bfloat16* Wt_c0 = Wt + 131072;
  __hip_bfloat16* Wt_g1 = Wt + 196608;
  __hip_bfloat16* Wt_c1 = Wt + 327680;
  __hip_bfloat16* Wt_q  = Wt + 393216;
  __hip_bfloat16* Wt_k  = Wt + 409600;
  __hip_bfloat16* Wt_v  = Wt + 425984;
  __hip_bfloat16* Wt_o  = Wt + 442368;

  const int MB = TOK / 128;     // 144
  const int LB = TOK / 4;       // 4608 (wave-per-token LN blocks)

  prep_w<<<dim3(128, 8), 256, 0, stream>>>(g0_Wg, g0_Wcx, g1_Wg, g1_Wcx,
                                           Wq, Wk, Wv, Wo, Wt);
  inproj_ln<<<LB, 256, 0, stream>>>(x_cgm, W_in, b_in, ln0_s, ln0_b, X, Xbf);

  // GRU block 0
  gemm_gru<<<dim3(MB, 6), 256, 0, stream>>>(Xbf, Wt_g0, g0_bg, Wt_c0, g0_bcx, Gb, Cb);
  gru_scan<<<B_, 512, 0, stream>>>(Gb, Cb, g0_Wch, g0_bch, Yb);
  ln_token_res<<<LB, 256, 0, stream>>>(Yb, ln1_s, ln1_b, X, X, Xbf);

  // GRU block 1
  gemm_gru<<<dim3(MB, 6), 256, 0, stream>>>(Xbf, Wt_g1, g1_bg, Wt_c1, g1_bcx, Gb, Cb);
  gru_scan<<<B_, 512, 0, stream>>>(Gb, Cb, g1_Wch, g1_bch, Yb);

  // fused LN2(+res) and attention-LN -> Obuf (bf16; C dead)
  ln_ln<<<LB, 256, 0, stream>>>(Yb, ln2_s, ln2_b, X, aln_s, aln_b, Obuf);

  // attention
  gemm_qkv<<<dim3(MB, 3), 256, 0, stream>>>(Obuf, Wt_q, bq, Wt_k, bk, Wt_v, bv,
                                            Qb, Kbuf, Vbuf);
  attn<<<dim3(B_, 4), 320, 0, stream>>>(Qb, Kbuf, Vbuf, AO);
  gemm_proj<<<dim3(MB, 2), 256, 0, stream>>>(AO, Wt_o, bo, X, X);

  // head
  head<<<B_, 256, 0, stream>>>(X, x_other, Wd1, bd1, lnd1_s, lnd1_b,
                               Wd2, bd2, lnd2_s, lnd2_b, Wout, bout,
                               (float*)d_out);
}